// Round 11
// baseline (6056.892 us; speedup 1.0000x reference)
//
#include <hip/hip_runtime.h>
#include <cstdint>

#define DEVI __device__ __forceinline__

typedef unsigned short u16;
typedef __bf16 bf16x8 __attribute__((ext_vector_type(8)));
typedef u16 u16x8 __attribute__((ext_vector_type(8)));
typedef float f32x4 __attribute__((ext_vector_type(4)));

// B=32, T=128 (127 decode steps), V=32000, E=256, U=AU=M=1024, S=128
#define NB 32
#define NT 127
#define NV 32000
#define NE 256
#define NU 1024
#define NBLK 256

DEVI float b2f(u16 h){ union{unsigned u; float f;} v; v.u = ((unsigned)h)<<16; return v.f; }
DEVI u16 f2b(float f){ union{float f; unsigned u;} v; v.f=f; unsigned u=v.u;
                       return (u16)((u + 0x7fffu + ((u>>16)&1u))>>16); }
DEVI float frcp(float x){ return __builtin_amdgcn_rcpf(x); }
DEVI float sigm(float x){ return frcp(1.f+__expf(-x)); }
DEVI float tanh_(float x){ return 1.f - 2.f*frcp(1.f+__expf(2.f*x)); }
#define MFMA __builtin_amdgcn_mfma_f32_16x16x32_bf16

// ---- batched coherent-bypass loads (sc0 sc1): issued wide, counted waits ----
DEVI void issue4(const unsigned* r0, const unsigned* r1, uint4* st){
  asm volatile(
    "global_load_dwordx4 %0, %4, off sc0 sc1\n\t"
    "global_load_dwordx4 %1, %4, off offset:16 sc0 sc1\n\t"
    "global_load_dwordx4 %2, %5, off sc0 sc1\n\t"
    "global_load_dwordx4 %3, %5, off offset:16 sc0 sc1"
    : "=&v"(st[0]), "=&v"(st[1]), "=&v"(st[2]), "=&v"(st[3])
    : "v"(r0), "v"(r1)
    : "memory");
}
DEVI void issue4q(const unsigned* q, uint4* st){
  asm volatile(
    "global_load_dwordx4 %0, %4, off sc0 sc1\n\t"
    "global_load_dwordx4 %1, %4, off offset:16 sc0 sc1\n\t"
    "global_load_dwordx4 %2, %4, off offset:32 sc0 sc1\n\t"
    "global_load_dwordx4 %3, %4, off offset:48 sc0 sc1"
    : "=&v"(st[0]), "=&v"(st[1]), "=&v"(st[2]), "=&v"(st[3])
    : "v"(q)
    : "memory");
}
// counted wait + sched fence (rule #18)
#define WAITC(imm) do{ \
  asm volatile("s_waitcnt vmcnt(" imm ")" ::: "memory"); \
  __builtin_amdgcn_sched_barrier(0); }while(0)

DEVI void bstore(unsigned* p, unsigned v){
  asm volatile("global_store_dword %0, %1, off sc0 sc1" :: "v"(p), "v"(v) : "memory");
}
DEVI void bstoref(float* p, float v){
  asm volatile("global_store_dword %0, %1, off sc0 sc1" :: "v"(p), "v"(v) : "memory");
}
DEVI uint4 bload4(const unsigned* p){
  uint4 f;
  asm volatile("global_load_dwordx4 %0, %1, off sc0 sc1\n\ts_waitcnt vmcnt(0)"
               : "=v"(f) : "v"(p) : "memory");
  return f;
}
DEVI unsigned bload1(const unsigned* p){
  unsigned f;
  asm volatile("global_load_dword %0, %1, off sc0 sc1\n\ts_waitcnt vmcnt(0)"
               : "=v"(f) : "v"(p) : "memory");
  return f;
}
// unpack 8 packed words (hi<<16|lo) -> hi/lo bf16x8
DEVI void unpack8(uint4 x, uint4 y, bf16x8& ah, bf16x8& al){
  union { unsigned u[4]; bf16x8 v; } H, L;
  H.u[0] = (x.y & 0xffff0000u) | (x.x >> 16);
  L.u[0] = (x.y << 16)         | (x.x & 0xffffu);
  H.u[1] = (x.w & 0xffff0000u) | (x.z >> 16);
  L.u[1] = (x.w << 16)         | (x.z & 0xffffu);
  H.u[2] = (y.y & 0xffff0000u) | (y.x >> 16);
  L.u[2] = (y.y << 16)         | (y.x & 0xffffu);
  H.u[3] = (y.w & 0xffff0000u) | (y.z >> 16);
  L.u[3] = (y.w << 16)         | (y.z & 0xffffu);
  ah = H.v; al = L.v;
}

// ---------------- small conversion kernels ----------------
__global__ void k_conv(const float* __restrict__ s, u16* __restrict__ d, int n){
  for (int i = blockIdx.x*256 + threadIdx.x; i < n; i += gridDim.x*256) d[i] = f2b(s[i]);
}
__global__ void k_split(const float* __restrict__ s, u16* __restrict__ dh, u16* __restrict__ dl, int n){
  for (int i = blockIdx.x*256 + threadIdx.x; i < n; i += gridDim.x*256){
    float v = s[i]; u16 hi = f2b(v); dh[i]=hi; dl[i]=f2b(v-b2f(hi));
  }
}
__global__ void k_pack(const float* __restrict__ s, unsigned* __restrict__ d, int n){
  for (int i = blockIdx.x*256 + threadIdx.x; i < n; i += gridDim.x*256){
    float v = s[i]; u16 hi = f2b(v); u16 lo = f2b(v-b2f(hi));
    d[i] = ((unsigned)hi<<16)|lo;
  }
}
__global__ void k_gather(const int* __restrict__ toks, const float* __restrict__ emb, u16* __restrict__ x){
  int i = blockIdx.x*256 + threadIdx.x;
  if (i >= NB*NT*NE) return;
  int bt = i>>8, e = i&255;
  int b = bt/NT, t = bt - b*NT;
  int tok = toks[b*128 + t];                 // dec_in = output_batch[:, :-1]
  x[i] = f2b(emb[(size_t)tok*NE + e]);
}
// transpose f32 (R x C, row stride rs) -> bf16 hi/lo (C x dstStride) at dst[c*dstStride+dstOff+r]
__global__ void k_transpose(const float* __restrict__ src, int rs,
                            u16* __restrict__ dh, u16* __restrict__ dl,
                            int dstStride, int dstOff){
  __shared__ float tile[32][33];
  int tc = blockIdx.x*32, tr = blockIdx.y*32;
  int tx = threadIdx.x & 31, ty = threadIdx.x >> 5;
  #pragma unroll
  for (int rr=0; rr<4; ++rr){
    int r = ty + rr*8;
    tile[r][tx] = src[(size_t)(tr+r)*rs + tc + tx];
  }
  __syncthreads();
  #pragma unroll
  for (int rr=0; rr<4; ++rr){
    int cl = ty + rr*8;
    float v = tile[tx][cl];
    u16 hi = f2b(v);
    size_t o = (size_t)(tc+cl)*dstStride + dstOff + tr + tx;
    dh[o] = hi;
    if (dl) dl[o] = f2b(v - b2f(hi));
  }
}
// transpose+add f32 C[1024][4096] (+addS) -> bf16 hi/lo dst[4096][1024]
__global__ void k_fuseT(const float* __restrict__ C, const float* __restrict__ addS,
                        u16* __restrict__ dh, u16* __restrict__ dl){
  __shared__ float tile[32][33];
  int tc = blockIdx.x*32, tr = blockIdx.y*32;
  int tx = threadIdx.x & 31, ty = threadIdx.x >> 5;
  #pragma unroll
  for (int rr=0; rr<4; ++rr){
    int r = ty + rr*8;
    float v = C[(size_t)(tr+r)*4096 + tc + tx];
    if (addS) v += addS[(size_t)(tr+r)*4096 + tc + tx];
    tile[r][tx] = v;
  }
  __syncthreads();
  #pragma unroll
  for (int rr=0; rr<4; ++rr){
    int cl = ty + rr*8;
    float v = tile[tx][cl];
    u16 hi = f2b(v);
    size_t o = (size_t)(tc+cl)*1024 + tr + tx;
    dh[o] = hi; dl[o] = f2b(v - b2f(hi));
  }
}

// ---------------- generic 64x64-tile bf16 MFMA GEMM (single-term) ----------------
template<int OUTF, int BIAS>
__global__ __launch_bounds__(256) void k_gemm64(
    const u16* __restrict__ A, int lda,
    const u16* __restrict__ Bt, int ldb,
    float* __restrict__ Cf, u16* __restrict__ Cb, int ldc,
    const float* __restrict__ bias, int M, int K)
{
  __shared__ __align__(16) u16 As[64][40];
  __shared__ __align__(16) u16 Bs[64][40];
  int n0 = blockIdx.x*64, m0 = blockIdx.y*64;
  int tid = threadIdx.x, lane = tid & 63, w = tid>>6;
  int lr = tid>>2, lk = (tid&3)*8;
  f32x4 acc[4] = {};
  for (int kk=0; kk<K; kk+=32){
    uint4 av = make_uint4(0,0,0,0);
    int row = m0 + lr;
    if (row < M) av = *(const uint4*)(A + (size_t)row*lda + kk + lk);
    *(uint4*)(&As[lr][lk]) = av;
    uint4 bv = *(const uint4*)(Bt + (size_t)(n0+lr)*ldb + kk + lk);
    *(uint4*)(&Bs[lr][lk]) = bv;
    __syncthreads();
    bf16x8 af = *(const bf16x8*)(&As[w*16 + (lane&15)][(lane>>4)*8]);
    #pragma unroll
    for (int ni=0; ni<4; ++ni){
      bf16x8 bfr = *(const bf16x8*)(&Bs[ni*16 + (lane&15)][(lane>>4)*8]);
      acc[ni] = MFMA(af, bfr, acc[ni], 0,0,0);
    }
    __syncthreads();
  }
  #pragma unroll
  for (int ni=0; ni<4; ++ni){
    #pragma unroll
    for (int r=0; r<4; ++r){
      int row = m0 + w*16 + (lane>>4)*4 + r;
      int col = n0 + ni*16 + (lane&15);
      if (row < M){
        float v = acc[ni][r];
        if (BIAS) v += bias[col];
        if (OUTF==0) Cf[(size_t)row*ldc + col] = v;
        else         Cb[(size_t)row*ldc + col] = f2b(v);
      }
    }
  }
}

// ---------------- 3-term split-precision 64x64 GEMM: (Ah+Al) x (Bh+Bl) ----------------
template<int OUTF>
__global__ __launch_bounds__(256) void k_gemm64s(
    const u16* __restrict__ Ah, const u16* __restrict__ Al, int lda,
    const u16* __restrict__ Bh, const u16* __restrict__ Bl, int ldb,
    float* __restrict__ Cf, u16* __restrict__ Cb, int ldc, int M, int K)
{
  __shared__ __align__(16) u16 Ash[64][40], Asl[64][40], Bsh[64][40], Bsl[64][40];
  int n0 = blockIdx.x*64, m0 = blockIdx.y*64;
  int tid = threadIdx.x, lane = tid & 63, w = tid>>6;
  int lr = tid>>2, lk = (tid&3)*8;
  f32x4 acc[4] = {};
  for (int kk=0; kk<K; kk+=32){
    uint4 avh = make_uint4(0,0,0,0), avl = make_uint4(0,0,0,0);
    int row = m0 + lr;
    if (row < M){
      avh = *(const uint4*)(Ah + (size_t)row*lda + kk + lk);
      avl = *(const uint4*)(Al + (size_t)row*lda + kk + lk);
    }
    *(uint4*)(&Ash[lr][lk]) = avh;
    *(uint4*)(&Asl[lr][lk]) = avl;
    *(uint4*)(&Bsh[lr][lk]) = *(const uint4*)(Bh + (size_t)(n0+lr)*ldb + kk + lk);
    *(uint4*)(&Bsl[lr][lk]) = *(const uint4*)(Bl + (size_t)(n0+lr)*ldb + kk + lk);
    __syncthreads();
    bf16x8 afh = *(const bf16x8*)(&Ash[w*16 + (lane&15)][(lane>>4)*8]);
    bf16x8 afl = *(const bf16x8*)(&Asl[w*16 + (lane&15)][(lane>>4)*8]);
    #pragma unroll
    for (int ni=0; ni<4; ++ni){
      bf16x8 bfh = *(const bf16x8*)(&Bsh[ni*16 + (lane&15)][(lane>>4)*8]);
      bf16x8 bfl = *(const bf16x8*)(&Bsl[ni*16 + (lane&15)][(lane>>4)*8]);
      acc[ni] = MFMA(afh, bfl, acc[ni], 0,0,0);
      acc[ni] = MFMA(afl, bfh, acc[ni], 0,0,0);
      acc[ni] = MFMA(afh, bfh, acc[ni], 0,0,0);
    }
    __syncthreads();
  }
  #pragma unroll
  for (int ni=0; ni<4; ++ni){
    #pragma unroll
    for (int r=0; r<4; ++r){
      int row = m0 + w*16 + (lane>>4)*4 + r;
      int col = n0 + ni*16 + (lane&15);
      if (row < M){
        float v = acc[ni][r];
        if (OUTF==0) Cf[(size_t)row*ldc + col] = v;
        else         Cb[(size_t)row*ldc + col] = f2b(v);
      }
    }
  }
}

// ---------------- persistent recurrence kernel ----------------
struct PP {
  const u16 *WzhTH, *WzhTL;   // [4096][1024]
  const u16 *WzcTH, *WzcTL;   // [4096][1024]
  const u16 *Wr0TH, *Wr0TL;   // [4096][1024] (t=0 h-weight = W_r^T)
  const u16 *WqT;             // [1024][1024]
  const u16 *xW;              // rows b*NT+t, 4096 cols (bf16, bias folded)
  const u16 *keys;            // [4096][1024]
  const u16 *aB;              // [4096][1024]
  const float *v_att;         // [1024]
  const unsigned *h0pk;       // [32][1024] packed hi|lo
  unsigned *hPk0, *hPk1;      // ping-pong packed h (bypass-exchanged)
  unsigned *ctxPk;            // [32][1024] packed (zero-init, bypass-exchanged)
  float *cbuf;                // [32][1024] block-private, cached
  float *qf;                  // [32][1024] bypass-exchanged
  float *scf;                 // [32][128] bypass-exchanged scores
  u16 *hcH, *hcL;             // [4096][2048] hist [h | ctx] cached (read post-kernel)
  unsigned *flags;            // [256] per-block generation flags (no atomics!)
};

// zero-RMW barrier: post own flag (plain bypass store), poll flags wide w/ backoff.
DEVI void post(unsigned* myflag, unsigned gen){
  asm volatile("s_waitcnt vmcnt(0)" ::: "memory");   // per-wave: all stores committed
  __syncthreads();                                    // whole block drained
  if (threadIdx.x == 0) bstore(myflag, gen);
}
// wait until flags[0..nflags) >= gen. Wave 0 polls: lane i checks flags[4i..4i+3].
DEVI void waitall(const unsigned* flags, unsigned gen, int nflags){
  if (threadIdx.x < 64){
    int idx = (int)threadIdx.x * 4;
    bool active = idx < nflags;
    const unsigned* fp = flags + (active ? idx : 0);
    for (;;){
      uint4 f = bload4(fp);
      bool ok = !active || (f.x>=gen && f.y>=gen && f.z>=gen && f.w>=gen);
      if (__all(ok)) break;
      __builtin_amdgcn_s_sleep(2);
    }
  }
  __syncthreads();
}
// wait until the 8 sibling flags (base + 8j) >= gen (narrow poll, lanes 0..7)
DEVI void waitsib(const unsigned* flags, unsigned gen, int base){
  if (threadIdx.x < 8){
    const unsigned* fp = flags + base + ((int)threadIdx.x << 3);
    for (;;){
      unsigned f = bload1(fp);
      if (__all(f >= gen)) break;
      __builtin_amdgcn_s_sleep(2);
    }
  }
  __syncthreads();
}

__global__ __launch_bounds__(512,1) void k_persist(PP p){
  __shared__ float smem[4096];   // zs[8][32][16] | C2: alig[128]+psum[8][128]+scl[128]
  float (*zs)[32][16] = (float(*)[32][16])smem;
  int tid = threadIdx.x, lane = tid&63, wv = tid>>6, blk = blockIdx.x;
  int l15 = lane&15, ko = (lane>>4)*8;
  unsigned* flags = p.flags;
  unsigned* myflag = flags + blk;

  // ============ register preloads (cached RO, never invalidated — no fences) =========
  // Every wave owns: h-part slice (k-window wv*128..wv*128+128 of Wzh; Wr0 at t=0)
  //                  ctx-part slice (same k-window of Wzc)
  int u0 = blk*4;
  int wrow = (l15>>2)*1024 + u0 + (l15&3);
  size_t woff = (size_t)wrow*1024 + wv*128 + ko;
  bf16x8 wHh[4], wLh[4], wHc[4], wLc[4];
  #pragma unroll
  for (int ki=0; ki<4; ++ki){
    wHh[ki] = *(const bf16x8*)(p.Wr0TH + woff + ki*32);
    wLh[ki] = *(const bf16x8*)(p.Wr0TL + woff + ki*32);
    wHc[ki] = *(const bf16x8*)(p.WzcTH + woff + ki*32);
    wLc[ki] = *(const bf16x8*)(p.WzcTL + woff + ki*32);
  }
  bf16x8 wq[4];
  int nq0 = (blk&63)*16;
  if (blk < 64){
    const u16* qg = p.WqT + (size_t)(nq0+l15)*1024 + wv*128 + ko;
    #pragma unroll
    for (int ki=0; ki<4; ++ki) wq[ki] = *(const bf16x8*)(qg + ki*32);
  }
  // phase-C mapping: co-locate a batch's 8 blocks on one XCD (XCD = blk%8)
  int m8 = blk>>3;
  int cb = (blk&7)*4 + (m8>>3);     // batch 0..31
  int c0 = (m8&7)*128;              // ctx col chunk
  int s0 = (m8&7)*16;               // score row chunk (C1)
  int sibbase = (blk&7) + 64*(blk>>6);  // siblings: sibbase + 8j, j=0..7
  int cp = 2*(tid&63), sq8 = tid>>6;
  unsigned av[16];
  #pragma unroll
  for (int si=0; si<16; ++si)
    av[si] = *(const unsigned*)(p.aB + (size_t)(cb*128 + sq8*16 + si)*1024 + c0 + cp);
  // keys slice for C1 (rows s0+wv*2+{0,1}) — register-pinned
  u16x8 kr[2][2];
  #pragma unroll
  for (int si=0; si<2; ++si){
    const u16* kp = p.keys + (size_t)(cb*128 + s0 + wv*2 + si)*1024 + lane*16;
    kr[si][0] = *(const u16x8*)kp;
    kr[si][1] = *(const u16x8*)(kp + 8);
  }
  // v_att slice (loop-invariant)
  float vr[16];
  #pragma unroll
  for (int j=0; j<4; ++j)
    *(float4*)&vr[j*4] = *(const float4*)(p.v_att + lane*16 + j*4);

  // ============ prologue: hacc_0 = h0 @ Wr0 (h-part of z_0), then swap Wr0->Wzh ======
  f32x4 hA0 = {}, hA1 = {};
  {
    const unsigned* b0 = p.h0pk + (size_t)l15*1024 + wv*128 + ko;
    const unsigned* b1 = b0 + 16*1024;
    uint4 st[3][4];
    issue4(b0,      b1,      st[0]);
    issue4(b0 + 32, b1 + 32, st[1]);
    #pragma unroll
    for (int ki=0; ki<4; ++ki){
      if (ki < 2){ issue4(b0 + (ki+2)*32, b1 + (ki+2)*32, st[(ki+2)%3]); WAITC("8"); }
      else if (ki == 2) WAITC("4");
      else              WAITC("0");
      bf16x8 a0h, a0l, a1h, a1l;
      unpack8(st[ki%3][0], st[ki%3][1], a0h, a0l);
      unpack8(st[ki%3][2], st[ki%3][3], a1h, a1l);
      hA0 = MFMA(a0h, wLh[ki], hA0, 0,0,0);
      hA0 = MFMA(a0l, wHh[ki], hA0, 0,0,0);
      hA0 = MFMA(a0h, wHh[ki], hA0, 0,0,0);
      hA1 = MFMA(a1h, wLh[ki], hA1, 0,0,0);
      hA1 = MFMA(a1l, wHh[ki], hA1, 0,0,0);
      hA1 = MFMA(a1h, wHh[ki], hA1, 0,0,0);
    }
    #pragma unroll
    for (int ki=0; ki<4; ++ki){
      wHh[ki] = *(const bf16x8*)(p.WzhTH + woff + ki*32);
      wLh[ki] = *(const bf16x8*)(p.WzhTL + woff + ki*32);
    }
  }

  for (int t=0; t<NT; ++t){
    unsigned* hoPk = (t&1)? p.hPk1 : p.hPk0;
    unsigned g1 = 4u*t + 1u, g2 = 4u*t + 2u, g3 = 4u*t + 3u, g4 = 4u*t + 4u;
    // ---- phase A (critical half): z = hacc + ctx@Wzc + xW -> gates -> h,c ----
    {
      const unsigned* b0 = p.ctxPk + (size_t)l15*1024 + wv*128 + ko;
      const unsigned* b1 = b0 + 16*1024;
      uint4 st[3][4];
      issue4(b0,      b1,      st[0]);
      issue4(b0 + 32, b1 + 32, st[1]);
      f32x4 acc0 = hA0, acc1 = hA1;
      #pragma unroll
      for (int ki=0; ki<4; ++ki){
        if (ki < 2){ issue4(b0 + (ki+2)*32, b1 + (ki+2)*32, st[(ki+2)%3]); WAITC("8"); }
        else if (ki == 2) WAITC("4");
        else              WAITC("0");
        bf16x8 a0h, a0l, a1h, a1l;
        unpack8(st[ki%3][0], st[ki%3][1], a0h, a0l);
        unpack8(st[ki%3][2], st[ki%3][3], a1h, a1l);
        acc0 = MFMA(a0h, wLc[ki], acc0, 0,0,0);
        acc0 = MFMA(a0l, wHc[ki], acc0, 0,0,0);
        acc0 = MFMA(a0h, wHc[ki], acc0, 0,0,0);
        acc1 = MFMA(a1h, wLc[ki], acc1, 0,0,0);
        acc1 = MFMA(a1l, wHc[ki], acc1, 0,0,0);
        acc1 = MFMA(a1h, wHc[ki], acc1, 0,0,0);
      }
      #pragma unroll
      for (int r=0; r<4; ++r){
        zs[wv][(lane>>4)*4 + r][l15]      = acc0[r];
        zs[wv][16 + (lane>>4)*4 + r][l15] = acc1[r];
      }
      __syncthreads();
      if (tid < 128){
        int b = tid>>2, du = tid&3;
        const u16* xw = p.xW + (size_t)(b*NT + t)*4096;
        float zg[4];
        #pragma unroll
        for (int g=0; g<4; ++g){
          float v = 0.f;
          #pragma unroll
          for (int w=0; w<8; ++w) v += zs[w][b][g*4+du];
          zg[g] = v + b2f(xw[g*1024 + u0 + du]);
        }
        float i_ = sigm(zg[0]), f_ = sigm(zg[1]), g_ = tanh_(zg[2]), o_ = sigm(zg[3]);
        int ci = b*NU + u0 + du;
        float cn = f_*p.cbuf[ci] + i_*g_;
        p.cbuf[ci] = cn;                       // block-private, cached
        float h = o_*tanh_(cn);
        u16 hi = f2b(h), lo = f2b(h - b2f(hi));
        bstore(&hoPk[ci], ((unsigned)hi<<16)|lo);     // bypass exchange
        size_t ho = (size_t)(b*NT + t)*2048 + u0 + du;
        p.hcH[ho] = hi; p.hcL[ho] = lo;               // history, cached
      }
    }
    post(myflag, g1);
    waitall(flags, g1, 256);
    // ---- phase B: q = h@W_q (blocks 0..63, critical) ----
    if (blk < 64){
      const unsigned* b0 = hoPk + (size_t)l15*1024 + wv*128 + ko;
      const unsigned* b1 = b0 + 16*1024;
      uint4 st[3][4];
      issue4(b0,      b1,      st[0]);
      issue4(b0 + 32, b1 + 32, st[1]);
      f32x4 acc0 = {}, acc1 = {};
      #pragma unroll
      for (int ki=0; ki<4; ++ki){
        if (ki < 2){ issue4(b0 + (ki+2)*32, b1 + (ki+2)*32, st[(ki+2)%3]); WAITC("8"); }
        else if (ki == 2) WAITC("4");
        else              WAITC("0");
        bf16x8 a0h, a0l, a1h, a1l;
        unpack8(st[ki%3][0], st[ki%3][1], a0h, a0l);
        unpack8(st[ki%3][2], st[ki%3][3], a1h, a1l);
        acc0 = MFMA(a0l, wq[ki], acc0, 0,0,0);
        acc0 = MFMA(a0h, wq[ki], acc0, 0,0,0);
        acc1 = MFMA(a1l, wq[ki], acc1, 0,0,0);
        acc1 = MFMA(a1h, wq[ki], acc1, 0,0,0);
      }
      #pragma unroll
      for (int r=0; r<4; ++r){
        zs[wv][(lane>>4)*4 + r][l15]      = acc0[r];
        zs[wv][16 + (lane>>4)*4 + r][l15] = acc1[r];
      }
      __syncthreads();
      {
        int b = tid>>4, c = tid&15;
        float v = 0.f;
        #pragma unroll
        for (int w=0; w<8; ++w) v += zs[w][b][c];
        bstoref(&p.qf[b*NU + nq0 + c], v);           // bypass exchange
      }
      post(myflag, g2);
    }
    // ---- overlap (off critical path): h-part of NEXT step's z = h_t @ Wzh ----
    if (t != NT-1){
      const unsigned* b0 = hoPk + (size_t)l15*1024 + wv*128 + ko;
      const unsigned* b1 = b0 + 16*1024;
      uint4 st[3][4];
      issue4(b0,      b1,      st[0]);
      issue4(b0 + 32, b1 + 32, st[1]);
      hA0 = f32x4{}; hA1 = f32x4{};
      #pragma unroll
      for (int ki=0; ki<4; ++ki){
        if (ki < 2){ issue4(b0 + (ki+2)*32, b1 + (ki+2)*32, st[(ki+2)%3]); WAITC("8"); }
        else if (ki == 2) WAITC("4");
        else              WAITC("0");
        bf16x8 a0h, a0l, a1h, a1l;
        unpack8(st[ki%3][0], st[ki%3][1], a0h, a0l);
        unpack8(st[ki%3][2], st[ki%3][3], a1h, a1l);
        hA0 = MFMA(a0h, wLh[ki], hA0, 0,0,0);
        hA0 = MFMA(a0l, wHh[ki], hA0, 0,0,0);
        hA0 = MFMA(a0h, wHh[ki], hA0, 0,0,0);
        hA1 = MFMA(a1h, wLh[ki], hA1, 0,0,0);
        hA1 = MFMA(a1l, wHh[ki], hA1, 0,0,0);
        hA1 = MFMA(a1h, wHh[ki], hA1, 0,0,0);
      }
    }
    waitall(flags, g2, 64);
    // ---- phase C1: own 16 score rows (keys in registers) ----
    {
      uint4 qb[4];
      issue4q((const unsigned*)(p.qf + cb*NU + lane*16), qb);
      WAITC("0");
      float qr[16];
      #pragma unroll
      for (int j=0; j<4; ++j){
        qr[j*4+0] = __uint_as_float(qb[j].x);
        qr[j*4+1] = __uint_as_float(qb[j].y);
        qr[j*4+2] = __uint_as_float(qb[j].z);
        qr[j*4+3] = __uint_as_float(qb[j].w);
      }
      #pragma unroll
      for (int si=0; si<2; ++si){
        float pv = 0.f;
        #pragma unroll
        for (int j=0; j<8; ++j) pv += vr[j]   * tanh_(b2f(kr[si][0][j]) + qr[j]);
        #pragma unroll
        for (int j=0; j<8; ++j) pv += vr[8+j] * tanh_(b2f(kr[si][1][j]) + qr[8+j]);
        #pragma unroll
        for (int off=32; off; off>>=1) pv += __shfl_xor(pv, off);
        if (lane==0) bstoref(&p.scf[cb*128 + s0 + wv*2 + si], pv);
      }
    }
    post(myflag, g3);
    waitsib(flags, g3, sibbase);
    // ---- phase C2: softmax + ctx chunk (aB in registers) ----
    {
      float* alig = smem;          // [128]
      float* psum = smem + 128;    // [8][128]
      float* scl  = smem + 1280;   // [128]
      if (tid < 32){
        uint4 sv = bload4((const unsigned*)(p.scf + cb*128) + tid*4);
        *(uint4*)&scl[tid*4] = sv;
      }
      __syncthreads();
      if (tid < 64){
        float sA = scl[tid], sB = scl[64 + tid];
        float m = fmaxf(sA, sB);
        #pragma unroll
        for (int off=32; off; off>>=1) m = fmaxf(m, __shfl_xor(m, off));
        float e0 = __expf(sA-m), e1 = __expf(sB-m);
        float sum = e0+e1;
        #pragma unroll
        for (int off=32; off; off>>=1) sum += __shfl_xor(sum, off);
        float inv = frcp(sum);
        alig[tid] = e0*inv; alig[tid+64] = e1*inv;
      }
      __syncthreads();
      {
        float ax = 0.f, ay = 0.f;
        #pragma unroll
        for (int si=0; si<16; ++si){
          unsigned kv = av[si];
          float al = alig[sq8*16 + si];
          ax += al*b2f((u16)(kv & 0xffffu));
          ay += al*b2f((u16)(kv >> 16));
        }
        psum[sq8*128 + cp]   = ax;
        psum[sq8*128 + cp+1] = ay;
      }
      __syncthreads();
      if (tid < 128){
        float v = 0.f;
        #pragma unroll
        for (int s8=0; s8<8; ++s8) v += psum[s8*128 + tid];
        int col = c0 + tid, ci = cb*NU + col;
        u16 hi = f2b(v), lo = f2b(v - b2f(hi));
        bstore(&p.ctxPk[ci], ((unsigned)hi<<16)|lo);       // bypass exchange
        size_t ho = (size_t)(cb*NT + t)*2048 + 1024 + col;
        p.hcH[ho] = hi; p.hcL[ho] = lo;                    // history, cached
      }
    }
    post(myflag, g4);
    waitall(flags, g4, 256);
  }
}

// ---------------- logits: 128x128-tile, BK=64, double-buffered reg-staged ----------------
#define LDSK 72
__global__ __launch_bounds__(256) void k_logits(
    const u16* __restrict__ A,   // [4096][1024]
    const u16* __restrict__ Bt,  // [32000][1024]
    const float* __restrict__ bias,
    float* __restrict__ C)
{
  __shared__ __align__(16) u16 As[128*LDSK];
  __shared__ __align__(16) u16 Bs[128*LDSK];
  int tid = threadIdx.x, lane = tid&63, wv = tid>>6;
  int m0 = blockIdx.y*128, n0 = blockIdx.x*128;
  int wr = (wv>>1)*64, wc = (wv&1)*64;
  int l15 = lane&15, ko = (lane>>4)*8;
  int srow = tid>>3, sc8 = (tid&7)*8;
  f32x4 acc[4][4] = {};
  uint4 a0[4], b0[4], a1[4], b1[4];

  #define LOADG(ar, br, kk) { \
    _Pragma("unroll") \
    for (int i=0;i<4;++i){ \
      ar[i] = *(const uint4*)(A  + (size_t)(m0+srow+i*32)*1024 + (kk) + sc8); \
      br[i] = *(const uint4*)(Bt + (size_t)(n0+srow+i*32)*1024 + (kk) + sc8); \
    } }
  #define STORES(ar, br) { \
    _Pragma("unroll") \
    for (int i=0;i<4;++i){ \
      *(uint4*)(&As[(srow+i*32)*LDSK + sc8]) = ar[i]; \
      *(uint4*)(&Bs[(srow+i*32)*LDSK + sc8]) = br[i]; \
    } }
  #define COMPUTE() { \
    _Pragma("unroll") \
    for (int ks=0; ks<2; ++ks){ \
      bf16x8 af[4], bf[4]; \
      _Pragma("unroll") \
      for (int i=0;i<4;++i){ \
        af[i] = *(const bf16x8*)(&As[(wr+i*16+l15)*LDSK + ks*32 + ko]); \
        bf[i] = *(const bf16x8*)(&Bs[(wc+i*16+l15)*LDSK + ks*32 + ko]); \
      } \
      _Pragma("unroll") \
      for (int mi=0;mi<4;++mi) \
        _Pragma("unroll") \
        for (int ni=0;ni<4;++ni) \
          acc[mi][ni] = MFMA(af[mi], bf[ni], acc[mi][ni], 0,0,0); \
    } }

  LOADG(a0, b0, 0);
  for (int kk=0; kk<1024; kk+=128){
    __syncthreads();
    STORES(a0, b0);
    if (kk+64 < 1024) LOADG(a1, b1, kk+64);
    __syncthreads();
    COMPUTE();
    __syncthreads();
    STORES(a1, b1);
    if (kk+128 < 1024) LOADG(a0, b0, kk+128);
    __syncthreads();
    COMPUTE();
  }
  #pragma unroll
  for (int mi=0; mi<4; ++mi){
    int row = m0 + wr + mi*16 + (lane>>4)*4;
    #pragma unroll
    for (int ni=0; ni<4; ++ni){
      int col = n0 + wc + ni*16 + l15;
      float bval = bias[col];
      #pragma unroll
      for (int r=0; r<4; ++r){
        if (row + r < NB*NT)
          C[(size_t)(row+r)*NV + col] = acc[mi][ni][r] + bval;
      }
    }
  }
  #undef LOADG
  #undef STORES
  #undef COMPUTE
}

// ---------------- host ----------------
extern "C" void kernel_launch(void* const* d_in, const int* in_sizes, int n_in,
                              void* d_out, int out_size, void* d_ws, size_t ws_size,
                              hipStream_t stream)
{
  (void)in_sizes; (void)n_in; (void)out_size; (void)ws_size;
  const int*   toks  = (const int*)  d_in[0];
  const float* a_in  = (const float*)d_in[1];
  const float* a_tx  = (const float*)d_in[2];
  const float* c_tx  = (const float*)d_in[3];
  const float* emb   = (const float*)d_in[4];
  const float* W_k   = (const float*)d_in[5];
  const float* W_r   = (const float*)d_in[6];
  const float* bvec  = (const float*)d_in[7];
  const float* W_m   = (const float*)d_in[8];
  const float* W_q   = (const float*)d_in[9];
  const float* v_att = (const float*)d_in[10];
  const float* W_a   = (const float*)d_in[11];
  const float* W_o   = (const float*)d_in[12];
  const float* b_o   = (const float*)d_in[13];
  float* out = (float*)d_out;

  char* p = (char*)d_ws;
  auto alloc = [&](size_t bytes)->char*{ char* r = p; p += (bytes + 255) & ~(size_t)255; return r; };

  u16* WzhTH = (u16*)alloc((size_t)4096*1024*2);
  u16* WzhTL = (u16*)alloc((size_t)4096*1024*2);
  u16* WzcTH = (u16*)alloc((size_t)4096*1024*2);
  u16* WzcTL = (u16*)alloc((size_t)4096*1024*2);
  u16* Wr0TH = (u16*)alloc((size_t)4096*1024*2);   // reused as outsH after persist
  u16* Wr0TL = (u16*)alloc((size_t)4096*1024*2);
  u16* WqT   = (u16*)alloc((size_t)1024*1024*2);
  u16* WaTH  = (u16*)alloc((size_t)1024*2048*2);
  u16* WaTL  = (u16*)alloc((size_t)1024*2048*2);
  u16* WmT   = (u16*)alloc((size_t)1024*1024*2);
  u16* WoT   = (u16*)alloc((size_t)NV*1024*2);
  u16* WkxT  = (u16*)alloc((size_t)4096*256*2);
  u16* xB    = (u16*)alloc((size_t)4096*256*2);
  u16* xWb   = (u16*)alloc((size_t)4096*4096*2);
  u16* aB    = (u16*)alloc((size_t)4096*1024*2);
  u16* keysB = (u16*)alloc((size_t)4096*1024*2);
  // union region: prep { WkaT h/l, WaRow h/l, tmpF } -> persist { hcH, hcL }
  char* uni  = alloc((size_t)44*1024*1024);
  u16* WkaTH  = (u16*)uni;
  u16* WkaTL  = WkaTH + (size_t)4096*1024;
  u16* WaRowH = WkaTL + (size_t)4096*1024;
  u16* WaRowL = WaRowH + (size_t)2048*1024;
  float* tmpF = (float*)(WaRowL + (size_t)2048*1024);
  u16* hcH = (u16*)uni;
  u16* hcL = hcH + (size_t)4096*2048;

  unsigned* h0pk  = (unsigned*)alloc((size_t)NB*NU*4);
  unsigned* hPk0  = (unsigned*)alloc((size_t)NB*NU*4);
  unsigned* hPk1  = (unsigned*)alloc((size_t)NB*NU*4);
  unsigned* ctxPk = (unsigned*)alloc((size_t)NB*NU*4);
  float* cbuf = (float*)alloc((size_t)NB*NU*4);
  float* qf   = (float*)alloc((size_t)NB*NU*4);
  float* scf  = (float*)alloc((size_t)NB*128*4);
  unsigned* flags = (unsigned*)alloc(4096);
  u16* outsH = Wr0TH;   // overlap (Wr0T dead after persist prologue)

  // ---- init ----
  (void)hipMemsetAsync(flags, 0, 4096, stream);
  (void)hipMemsetAsync(ctxPk, 0, (size_t)NB*NU*4, stream);
  (void)hipMemcpyAsync(cbuf, c_tx, (size_t)NB*NU*4, hipMemcpyDeviceToDevice, stream);
  k_pack<<<128,256,0,stream>>>(a_tx, h0pk, NB*NU);
  k_split<<<2048,256,0,stream>>>(W_a, WaRowH, WaRowL, 2048*1024);
  k_gather<<<(NB*NT*NE)/256,256,0,stream>>>(toks, emb, xB);
  k_conv<<<2048,256,0,stream>>>(a_in, aB, NB*128*NU);

  // ---- weight transposes ----
  k_transpose<<<dim3(128,32),256,0,stream>>>(W_k + (size_t)256*4096, 4096, WkaTH, WkaTL, 1024, 0);
  k_transpose<<<dim3(128,32),256,0,stream>>>(W_r, 4096, Wr0TH, Wr0TL, 1024, 0);
  k_transpose<<<dim3(32,32),256,0,stream>>>(W_q, 1024, WqT, nullptr, 1024, 0);
  k_transpose<<<dim3(32,64),256,0,stream>>>(W_a, 1024, WaTH, WaTL, 2048, 0);
  k_transpose<<<dim3(32,32),256,0,stream>>>(W_m, 1024, WmT, nullptr, 1024, 0);
  k_transpose<<<dim3(1000,32),256,0,stream>>>(W_o, NV, WoT, nullptr, 1024, 0);
  k_transpose<<<dim3(128,8),256,0,stream>>>(W_k, 4096, WkxT, nullptr, 256, 0);

  // ---- precompute GEMMs ----
  // keys = a @ W_m
  k_gemm64<1,0><<<dim3(16,64),256,0,stream>>>(aB, 1024, WmT, 1024, nullptr, keysB, 1024, nullptr, 4096, 1024);
  // xW = x @ W_k[0:256] + b
  k_gemm64<1,1><<<dim3(64,64),256,0,stream>>>(xB, 256, WkxT, 256, nullptr, xWb, 4096, bvec, NB*NT, 256);
  // Wzh = W_r + W_a[0:1024] @ Wk_attn  (3-term split, f32, then transpose+split)
  k_gemm64s<0><<<dim3(64,16),256,0,stream>>>(WaRowH, WaRowL, 1024, WkaTH, WkaTL, 1024,
                                             tmpF, nullptr, 4096, 1024, 1024);
  k_fuseT<<<dim3(128,32),256,0,stream>>>(tmpF, W_r, WzhTH, WzhTL);
  // Wzc = W_a[1024:2048] @ Wk_attn
  k_gemm64s<0><<<dim3(64,16),256,0,stream>>>(WaRowH + (size_t)1024*1024, WaRowL + (size_t)1024*1024, 1024,
                                             WkaTH, WkaTL, 1024, tmpF, nullptr, 4096, 1024, 1024);
  k_fuseT<<<dim3(128,32),256,0,stream>>>(tmpF, nullptr, WzcTH, WzcTL);

  // ---- persistent recurrence ----
  PP pp;
  pp.WzhTH=WzhTH; pp.WzhTL=WzhTL; pp.WzcTH=WzcTH; pp.WzcTL=WzcTL;
  pp.Wr0TH=Wr0TH; pp.Wr0TL=Wr0TL; pp.WqT=WqT; pp.xW=xWb;
  pp.keys=keysB; pp.aB=aB; pp.v_att=v_att;
  pp.h0pk=h0pk; pp.hPk0=hPk0; pp.hPk1=hPk1; pp.ctxPk=ctxPk;
  pp.cbuf=cbuf; pp.qf=qf; pp.scf=scf;
  pp.hcH=hcH; pp.hcL=hcL; pp.flags=flags;
  k_persist<<<NBLK,512,0,stream>>>(pp);

  // ---- outs = [h|ctx] @ W_a  (3-term split, bf16 out) ----
  k_gemm64s<1><<<dim3(16,64),256,0,stream>>>(hcH, hcL, 2048, WaTH, WaTL, 2048,
                                             nullptr, outsH, 1024, NB*NT, 2048);

  // ---- logits = outs @ W_o + b_o ----
  k_logits<<<dim3(NV/128, 32),256,0,stream>>>(outsH, WoT, b_o, out);
}

// Round 12
// 5544.891 us; speedup vs baseline: 1.0923x; 1.0923x over previous
//
#include <hip/hip_runtime.h>
#include <cstdint>

#define DEVI __device__ __forceinline__

typedef unsigned short u16;
typedef __bf16 bf16x8 __attribute__((ext_vector_type(8)));
typedef u16 u16x8 __attribute__((ext_vector_type(8)));
typedef float f32x4 __attribute__((ext_vector_type(4)));

// B=32, T=128 (127 decode steps), V=32000, E=256, U=AU=M=1024, S=128
#define NB 32
#define NT 127
#define NV 32000
#define NE 256
#define NU 1024
#define NBLK 256

DEVI float b2f(u16 h){ union{unsigned u; float f;} v; v.u = ((unsigned)h)<<16; return v.f; }
DEVI u16 f2b(float f){ union{float f; unsigned u;} v; v.f=f; unsigned u=v.u;
                       return (u16)((u + 0x7fffu + ((u>>16)&1u))>>16); }
DEVI float frcp(float x){ return __builtin_amdgcn_rcpf(x); }
DEVI float sigm(float x){ return frcp(1.f+__expf(-x)); }
DEVI float tanh_(float x){ return 1.f - 2.f*frcp(1.f+__expf(2.f*x)); }
#define MFMA __builtin_amdgcn_mfma_f32_16x16x32_bf16

// ---- batched coherent-bypass loads (sc0 sc1): issued wide, counted waits ----
DEVI void issue4(const unsigned* r0, const unsigned* r1, uint4* st){
  asm volatile(
    "global_load_dwordx4 %0, %4, off sc0 sc1\n\t"
    "global_load_dwordx4 %1, %4, off offset:16 sc0 sc1\n\t"
    "global_load_dwordx4 %2, %5, off sc0 sc1\n\t"
    "global_load_dwordx4 %3, %5, off offset:16 sc0 sc1"
    : "=&v"(st[0]), "=&v"(st[1]), "=&v"(st[2]), "=&v"(st[3])
    : "v"(r0), "v"(r1)
    : "memory");
}
DEVI void issue4q(const unsigned* q, uint4* st){
  asm volatile(
    "global_load_dwordx4 %0, %4, off sc0 sc1\n\t"
    "global_load_dwordx4 %1, %4, off offset:16 sc0 sc1\n\t"
    "global_load_dwordx4 %2, %4, off offset:32 sc0 sc1\n\t"
    "global_load_dwordx4 %3, %4, off offset:48 sc0 sc1"
    : "=&v"(st[0]), "=&v"(st[1]), "=&v"(st[2]), "=&v"(st[3])
    : "v"(q)
    : "memory");
}
// counted wait + sched fence (rule #18)
#define WAITC(imm) do{ \
  asm volatile("s_waitcnt vmcnt(" imm ")" ::: "memory"); \
  __builtin_amdgcn_sched_barrier(0); }while(0)

DEVI void bstore(unsigned* p, unsigned v){
  asm volatile("global_store_dword %0, %1, off sc0 sc1" :: "v"(p), "v"(v) : "memory");
}
DEVI void bstoref(float* p, float v){
  asm volatile("global_store_dword %0, %1, off sc0 sc1" :: "v"(p), "v"(v) : "memory");
}
DEVI uint4 bload4(const unsigned* p){
  uint4 f;
  asm volatile("global_load_dwordx4 %0, %1, off sc0 sc1\n\ts_waitcnt vmcnt(0)"
               : "=v"(f) : "v"(p) : "memory");
  return f;
}
DEVI unsigned bload1(const unsigned* p){
  unsigned f;
  asm volatile("global_load_dword %0, %1, off sc0 sc1\n\ts_waitcnt vmcnt(0)"
               : "=v"(f) : "v"(p) : "memory");
  return f;
}
// unpack 8 packed words (hi<<16|lo) -> hi/lo bf16x8
DEVI void unpack8(uint4 x, uint4 y, bf16x8& ah, bf16x8& al){
  union { unsigned u[4]; bf16x8 v; } H, L;
  H.u[0] = (x.y & 0xffff0000u) | (x.x >> 16);
  L.u[0] = (x.y << 16)         | (x.x & 0xffffu);
  H.u[1] = (x.w & 0xffff0000u) | (x.z >> 16);
  L.u[1] = (x.w << 16)         | (x.z & 0xffffu);
  H.u[2] = (y.y & 0xffff0000u) | (y.x >> 16);
  L.u[2] = (y.y << 16)         | (y.x & 0xffffu);
  H.u[3] = (y.w & 0xffff0000u) | (y.z >> 16);
  L.u[3] = (y.w << 16)         | (y.z & 0xffffu);
  ah = H.v; al = L.v;
}

// ---------------- small conversion kernels ----------------
__global__ void k_conv(const float* __restrict__ s, u16* __restrict__ d, int n){
  for (int i = blockIdx.x*256 + threadIdx.x; i < n; i += gridDim.x*256) d[i] = f2b(s[i]);
}
__global__ void k_split(const float* __restrict__ s, u16* __restrict__ dh, u16* __restrict__ dl, int n){
  for (int i = blockIdx.x*256 + threadIdx.x; i < n; i += gridDim.x*256){
    float v = s[i]; u16 hi = f2b(v); dh[i]=hi; dl[i]=f2b(v-b2f(hi));
  }
}
__global__ void k_pack(const float* __restrict__ s, unsigned* __restrict__ d, int n){
  for (int i = blockIdx.x*256 + threadIdx.x; i < n; i += gridDim.x*256){
    float v = s[i]; u16 hi = f2b(v); u16 lo = f2b(v-b2f(hi));
    d[i] = ((unsigned)hi<<16)|lo;
  }
}
__global__ void k_gather(const int* __restrict__ toks, const float* __restrict__ emb, u16* __restrict__ x){
  int i = blockIdx.x*256 + threadIdx.x;
  if (i >= NB*NT*NE) return;
  int bt = i>>8, e = i&255;
  int b = bt/NT, t = bt - b*NT;
  int tok = toks[b*128 + t];                 // dec_in = output_batch[:, :-1]
  x[i] = f2b(emb[(size_t)tok*NE + e]);
}
// transpose f32 (R x C, row stride rs) -> bf16 hi/lo (C x dstStride) at dst[c*dstStride+dstOff+r]
__global__ void k_transpose(const float* __restrict__ src, int rs,
                            u16* __restrict__ dh, u16* __restrict__ dl,
                            int dstStride, int dstOff){
  __shared__ float tile[32][33];
  int tc = blockIdx.x*32, tr = blockIdx.y*32;
  int tx = threadIdx.x & 31, ty = threadIdx.x >> 5;
  #pragma unroll
  for (int rr=0; rr<4; ++rr){
    int r = ty + rr*8;
    tile[r][tx] = src[(size_t)(tr+r)*rs + tc + tx];
  }
  __syncthreads();
  #pragma unroll
  for (int rr=0; rr<4; ++rr){
    int cl = ty + rr*8;
    float v = tile[tx][cl];
    u16 hi = f2b(v);
    size_t o = (size_t)(tc+cl)*dstStride + dstOff + tr + tx;
    dh[o] = hi;
    if (dl) dl[o] = f2b(v - b2f(hi));
  }
}
// transpose+add f32 C[1024][4096] (+addS) -> bf16 hi/lo dst[4096][1024]
__global__ void k_fuseT(const float* __restrict__ C, const float* __restrict__ addS,
                        u16* __restrict__ dh, u16* __restrict__ dl){
  __shared__ float tile[32][33];
  int tc = blockIdx.x*32, tr = blockIdx.y*32;
  int tx = threadIdx.x & 31, ty = threadIdx.x >> 5;
  #pragma unroll
  for (int rr=0; rr<4; ++rr){
    int r = ty + rr*8;
    float v = C[(size_t)(tr+r)*4096 + tc + tx];
    if (addS) v += addS[(size_t)(tr+r)*4096 + tc + tx];
    tile[r][tx] = v;
  }
  __syncthreads();
  #pragma unroll
  for (int rr=0; rr<4; ++rr){
    int cl = ty + rr*8;
    float v = tile[tx][cl];
    u16 hi = f2b(v);
    size_t o = (size_t)(tc+cl)*1024 + tr + tx;
    dh[o] = hi; dl[o] = f2b(v - b2f(hi));
  }
}

// ---------------- generic 64x64-tile bf16 MFMA GEMM (single-term) ----------------
template<int OUTF, int BIAS>
__global__ __launch_bounds__(256) void k_gemm64(
    const u16* __restrict__ A, int lda,
    const u16* __restrict__ Bt, int ldb,
    float* __restrict__ Cf, u16* __restrict__ Cb, int ldc,
    const float* __restrict__ bias, int M, int K)
{
  __shared__ __align__(16) u16 As[64][40];
  __shared__ __align__(16) u16 Bs[64][40];
  int n0 = blockIdx.x*64, m0 = blockIdx.y*64;
  int tid = threadIdx.x, lane = tid & 63, w = tid>>6;
  int lr = tid>>2, lk = (tid&3)*8;
  f32x4 acc[4] = {};
  for (int kk=0; kk<K; kk+=32){
    uint4 av = make_uint4(0,0,0,0);
    int row = m0 + lr;
    if (row < M) av = *(const uint4*)(A + (size_t)row*lda + kk + lk);
    *(uint4*)(&As[lr][lk]) = av;
    uint4 bv = *(const uint4*)(Bt + (size_t)(n0+lr)*ldb + kk + lk);
    *(uint4*)(&Bs[lr][lk]) = bv;
    __syncthreads();
    bf16x8 af = *(const bf16x8*)(&As[w*16 + (lane&15)][(lane>>4)*8]);
    #pragma unroll
    for (int ni=0; ni<4; ++ni){
      bf16x8 bfr = *(const bf16x8*)(&Bs[ni*16 + (lane&15)][(lane>>4)*8]);
      acc[ni] = MFMA(af, bfr, acc[ni], 0,0,0);
    }
    __syncthreads();
  }
  #pragma unroll
  for (int ni=0; ni<4; ++ni){
    #pragma unroll
    for (int r=0; r<4; ++r){
      int row = m0 + w*16 + (lane>>4)*4 + r;
      int col = n0 + ni*16 + (lane&15);
      if (row < M){
        float v = acc[ni][r];
        if (BIAS) v += bias[col];
        if (OUTF==0) Cf[(size_t)row*ldc + col] = v;
        else         Cb[(size_t)row*ldc + col] = f2b(v);
      }
    }
  }
}

// ------- 128x128-tile, BK=32, 3-term split GEMM: (Ah+Al) x (Bh+Bl), N mult of 128 -------
template<int OUTF>
__global__ __launch_bounds__(256) void k_gemm128s(
    const u16* __restrict__ Ah, const u16* __restrict__ Al, int lda,
    const u16* __restrict__ Bh, const u16* __restrict__ Bl, int ldb,
    float* __restrict__ Cf, u16* __restrict__ Cb, int ldc, int M, int K)
{
  __shared__ __align__(16) u16 AsH[128][40], AsL[128][40], BsH[128][40], BsL[128][40];
  int n0 = blockIdx.x*128, m0 = blockIdx.y*128;
  int tid = threadIdx.x, lane = tid&63, wv = tid>>6;
  int lr = tid>>1, lk = (tid&1)*16;
  int wr = (wv>>1)*64, wc = (wv&1)*64;
  int l15 = lane&15, ko = (lane>>4)*8;
  f32x4 acc[4][4] = {};
  for (int kk=0; kk<K; kk+=32){
    uint4 z = make_uint4(0,0,0,0);
    uint4 ah0=z, ah1=z, al0=z, al1=z;
    int row = m0 + lr;
    if (row < M){
      ah0 = *(const uint4*)(Ah + (size_t)row*lda + kk + lk);
      ah1 = *(const uint4*)(Ah + (size_t)row*lda + kk + lk + 8);
      al0 = *(const uint4*)(Al + (size_t)row*lda + kk + lk);
      al1 = *(const uint4*)(Al + (size_t)row*lda + kk + lk + 8);
    }
    *(uint4*)&AsH[lr][lk]   = ah0;
    *(uint4*)&AsH[lr][lk+8] = ah1;
    *(uint4*)&AsL[lr][lk]   = al0;
    *(uint4*)&AsL[lr][lk+8] = al1;
    *(uint4*)&BsH[lr][lk]   = *(const uint4*)(Bh + (size_t)(n0+lr)*ldb + kk + lk);
    *(uint4*)&BsH[lr][lk+8] = *(const uint4*)(Bh + (size_t)(n0+lr)*ldb + kk + lk + 8);
    *(uint4*)&BsL[lr][lk]   = *(const uint4*)(Bl + (size_t)(n0+lr)*ldb + kk + lk);
    *(uint4*)&BsL[lr][lk+8] = *(const uint4*)(Bl + (size_t)(n0+lr)*ldb + kk + lk + 8);
    __syncthreads();
    bf16x8 afh[4], afl[4], bfh[4], bfl[4];
    #pragma unroll
    for (int i=0;i<4;++i){
      afh[i] = *(const bf16x8*)&AsH[wr+i*16+l15][ko];
      afl[i] = *(const bf16x8*)&AsL[wr+i*16+l15][ko];
      bfh[i] = *(const bf16x8*)&BsH[wc+i*16+l15][ko];
      bfl[i] = *(const bf16x8*)&BsL[wc+i*16+l15][ko];
    }
    #pragma unroll
    for (int mi=0;mi<4;++mi)
      #pragma unroll
      for (int ni=0;ni<4;++ni){
        acc[mi][ni] = MFMA(afh[mi], bfl[ni], acc[mi][ni], 0,0,0);
        acc[mi][ni] = MFMA(afl[mi], bfh[ni], acc[mi][ni], 0,0,0);
        acc[mi][ni] = MFMA(afh[mi], bfh[ni], acc[mi][ni], 0,0,0);
      }
    __syncthreads();
  }
  #pragma unroll
  for (int mi=0;mi<4;++mi){
    int rowb = m0 + wr + mi*16 + (lane>>4)*4;
    #pragma unroll
    for (int ni=0;ni<4;++ni){
      int col = n0 + wc + ni*16 + l15;
      #pragma unroll
      for (int r=0;r<4;++r){
        if (rowb + r < M){
          float v = acc[mi][ni][r];
          if (OUTF==0) Cf[(size_t)(rowb+r)*ldc + col] = v;
          else         Cb[(size_t)(rowb+r)*ldc + col] = f2b(v);
        }
      }
    }
  }
}

// ---------------- persistent recurrence kernel ----------------
struct PP {
  const u16 *WzhTH, *WzhTL;   // [4096][1024]
  const u16 *WzcTH, *WzcTL;   // [4096][1024]
  const u16 *Wr0TH, *Wr0TL;   // [4096][1024] (t=0 h-weight = W_r^T)
  const u16 *WqT;             // [1024][1024]
  const u16 *xW;              // rows b*NT+t, 4096 cols (bf16, bias folded)
  const u16 *keys;            // [4096][1024]
  const u16 *aB;              // [4096][1024]
  const float *v_att;         // [1024]
  const float *c0f;           // [32][1024] initial c (f32)
  const unsigned *h0pk;       // [32][1024] packed hi|lo
  unsigned *hPk0, *hPk1;      // ping-pong packed h (bypass-exchanged)
  unsigned *ctxPk;            // [32][1024] packed (zero-init, bypass-exchanged)
  float *qf;                  // [32][1024] bypass-exchanged
  float *scf;                 // [32][128] bypass-exchanged scores
  u16 *hcH, *hcL;             // [4096][2048] hist [h | ctx] cached (read post-kernel)
  unsigned *flags;            // [256] per-block generation flags (no atomics!)
};

// zero-RMW barrier: post own flag (plain bypass store), poll flags wide w/ backoff.
DEVI void post(unsigned* myflag, unsigned gen){
  asm volatile("s_waitcnt vmcnt(0)" ::: "memory");   // per-wave: all stores committed
  __syncthreads();                                    // whole block drained
  if (threadIdx.x == 0) bstore(myflag, gen);
}
// wait until flags[0..nflags) >= gen. Wave 0 polls: lane i checks flags[4i..4i+3].
DEVI void waitall(const unsigned* flags, unsigned gen, int nflags){
  if (threadIdx.x < 64){
    int idx = (int)threadIdx.x * 4;
    bool active = idx < nflags;
    const unsigned* fp = flags + (active ? idx : 0);
    for (;;){
      uint4 f = bload4(fp);
      bool ok = !active || (f.x>=gen && f.y>=gen && f.z>=gen && f.w>=gen);
      if (__all(ok)) break;
      __builtin_amdgcn_s_sleep(4);
    }
  }
  __syncthreads();
}
// wait until the 8 sibling flags (base + 8j) >= gen (narrow poll, lanes 0..7)
DEVI void waitsib(const unsigned* flags, unsigned gen, int base){
  if (threadIdx.x < 8){
    const unsigned* fp = flags + base + ((int)threadIdx.x << 3);
    for (;;){
      unsigned f = bload1(fp);
      if (__all(f >= gen)) break;
      __builtin_amdgcn_s_sleep(2);
    }
  }
  __syncthreads();
}

__global__ __launch_bounds__(512,1) void k_persist(PP p){
  __shared__ float smem[4096];   // zs[8][32][16] | C2: alig[128]+psum[8][128]+scl[128]
  float (*zs)[32][16] = (float(*)[32][16])smem;
  int tid = threadIdx.x, lane = tid&63, wv = tid>>6, blk = blockIdx.x;
  int l15 = lane&15, ko = (lane>>4)*8;
  unsigned* flags = p.flags;
  unsigned* myflag = flags + blk;

  // ============ register preloads (cached RO, never invalidated — no fences) =========
  int u0 = blk*4;
  int wrow = (l15>>2)*1024 + u0 + (l15&3);
  size_t woff = (size_t)wrow*1024 + (wv&3)*256 + ko;
  const u16 *whG = (wv<4 ? p.Wr0TH : p.WzcTH) + woff;
  const u16 *wlG = (wv<4 ? p.Wr0TL : p.WzcTL) + woff;
  bf16x8 wH[8], wL[8];
  #pragma unroll
  for (int ki=0; ki<8; ++ki){
    wH[ki] = *(const bf16x8*)(whG + ki*32);
    wL[ki] = *(const bf16x8*)(wlG + ki*32);
  }
  bf16x8 wq[4];
  int nq0 = (blk&63)*16;
  if (blk < 64){
    const u16* qg = p.WqT + (size_t)(nq0+l15)*1024 + wv*128 + ko;
    #pragma unroll
    for (int ki=0; ki<4; ++ki) wq[ki] = *(const bf16x8*)(qg + ki*32);
  }
  // block-private LSTM cell state (register-resident!)
  float creg = 0.f;
  if (tid < 128) creg = p.c0f[(tid>>2)*NU + u0 + (tid&3)];
  // phase-C mapping: co-locate a batch's 8 blocks on one XCD (XCD = blk%8)
  int m8 = blk>>3;
  int cb = (blk&7)*4 + (m8>>3);     // batch 0..31
  int c0 = (m8&7)*128;              // ctx col chunk
  int s0 = (m8&7)*16;               // score row chunk (C1)
  int sibbase = (blk&7) + 64*(blk>>6);  // siblings: sibbase + 8j, j=0..7
  int cp = 2*(tid&63), sq8 = tid>>6;
  unsigned av[16];
  #pragma unroll
  for (int si=0; si<16; ++si)
    av[si] = *(const unsigned*)(p.aB + (size_t)(cb*128 + sq8*16 + si)*1024 + c0 + cp);
  // keys slice for C1 (rows s0+wv*2+{0,1}) — register-pinned, no per-step L2 traffic
  u16x8 kr[2][2];
  #pragma unroll
  for (int si=0; si<2; ++si){
    const u16* kp = p.keys + (size_t)(cb*128 + s0 + wv*2 + si)*1024 + lane*16;
    kr[si][0] = *(const u16x8*)kp;
    kr[si][1] = *(const u16x8*)(kp + 8);
  }
  // v_att slice (loop-invariant)
  float vr[16];
  #pragma unroll
  for (int j=0; j<4; ++j)
    *(float4*)&vr[j*4] = *(const float4*)(p.v_att + lane*16 + j*4);

  const unsigned* hpPk = p.h0pk;
  for (int t=0; t<NT; ++t){
    unsigned* hoPk = (t&1)? p.hPk1 : p.hPk0;
    unsigned g1 = 4u*t + 1u, g2 = 4u*t + 2u, g3 = 4u*t + 3u, g4 = 4u*t + 4u;
    // ---- phase A: z = xW + h@Wzh + ctx@Wzc -> gates -> h,c ----
    {
      // prefetch this step's xW gate biases early (cached; hides under bypass chain)
      float xw0=0.f, xw1=0.f, xw2=0.f, xw3=0.f;
      if (tid < 128){
        const u16* xw = p.xW + (size_t)((tid>>2)*NT + t)*4096 + u0 + (tid&3);
        xw0 = b2f(xw[0]); xw1 = b2f(xw[1024]); xw2 = b2f(xw[2048]); xw3 = b2f(xw[3072]);
      }
      const unsigned* Apk = (wv<4)? hpPk : p.ctxPk;
      int kb = (wv&3)*256;
      const unsigned* b0 = Apk + (size_t)l15*1024 + kb + ko;
      const unsigned* b1 = b0 + 16*1024;
      uint4 st[3][4];
      issue4(b0,      b1,      st[0]);
      issue4(b0 + 32, b1 + 32, st[1]);
      f32x4 acc0 = {}, acc1 = {};
      #pragma unroll
      for (int ki=0; ki<8; ++ki){
        if (ki < 6){ issue4(b0 + (ki+2)*32, b1 + (ki+2)*32, st[(ki+2)%3]); WAITC("8"); }
        else if (ki == 6) WAITC("4");
        else              WAITC("0");
        bf16x8 a0h, a0l, a1h, a1l;
        unpack8(st[ki%3][0], st[ki%3][1], a0h, a0l);
        unpack8(st[ki%3][2], st[ki%3][3], a1h, a1l);
        acc0 = MFMA(a0h, wL[ki], acc0, 0,0,0);
        acc0 = MFMA(a0l, wH[ki], acc0, 0,0,0);
        acc0 = MFMA(a0h, wH[ki], acc0, 0,0,0);
        acc1 = MFMA(a1h, wL[ki], acc1, 0,0,0);
        acc1 = MFMA(a1l, wH[ki], acc1, 0,0,0);
        acc1 = MFMA(a1h, wH[ki], acc1, 0,0,0);
      }
      if (t == 0 && wv < 4){   // swap Wr0 -> steady-state Wzh (hidden under B/C)
        const u16* nh = p.WzhTH + woff;
        const u16* nl = p.WzhTL + woff;
        #pragma unroll
        for (int ki=0; ki<8; ++ki){
          wH[ki] = *(const bf16x8*)(nh + ki*32);
          wL[ki] = *(const bf16x8*)(nl + ki*32);
        }
      }
      #pragma unroll
      for (int r=0; r<4; ++r){
        zs[wv][(lane>>4)*4 + r][l15]      = acc0[r];
        zs[wv][16 + (lane>>4)*4 + r][l15] = acc1[r];
      }
      __syncthreads();
      if (tid < 128){
        int b = tid>>2, du = tid&3;
        float zg[4];
        #pragma unroll
        for (int g=0; g<4; ++g){
          float v = 0.f;
          #pragma unroll
          for (int w=0; w<8; ++w) v += zs[w][b][g*4+du];
          zg[g] = v;
        }
        zg[0] += xw0; zg[1] += xw1; zg[2] += xw2; zg[3] += xw3;
        float i_ = sigm(zg[0]), f_ = sigm(zg[1]), g_ = tanh_(zg[2]), o_ = sigm(zg[3]);
        int ci = b*NU + u0 + du;
        float cn = f_*creg + i_*g_;
        creg = cn;                             // register-resident cell state
        float h = o_*tanh_(cn);
        u16 hi = f2b(h), lo = f2b(h - b2f(hi));
        bstore(&hoPk[ci], ((unsigned)hi<<16)|lo);     // bypass exchange
        size_t ho = (size_t)(b*NT + t)*2048 + u0 + du;
        p.hcH[ho] = hi; p.hcL[ho] = lo;               // history, cached
      }
    }
    post(myflag, g1);
    // ---- phase B: q = h@W_q (blocks 0..63) ----
    if (blk < 64){
      waitall(flags, g1, 256);
      const unsigned* b0 = hoPk + (size_t)l15*1024 + wv*128 + ko;
      const unsigned* b1 = b0 + 16*1024;
      uint4 st[3][4];
      issue4(b0,      b1,      st[0]);
      issue4(b0 + 32, b1 + 32, st[1]);
      f32x4 acc0 = {}, acc1 = {};
      #pragma unroll
      for (int ki=0; ki<4; ++ki){
        if (ki < 2){ issue4(b0 + (ki+2)*32, b1 + (ki+2)*32, st[(ki+2)%3]); WAITC("8"); }
        else if (ki == 2) WAITC("4");
        else              WAITC("0");
        bf16x8 a0h, a0l, a1h, a1l;
        unpack8(st[ki%3][0], st[ki%3][1], a0h, a0l);
        unpack8(st[ki%3][2], st[ki%3][3], a1h, a1l);
        acc0 = MFMA(a0l, wq[ki], acc0, 0,0,0);
        acc0 = MFMA(a0h, wq[ki], acc0, 0,0,0);
        acc1 = MFMA(a1l, wq[ki], acc1, 0,0,0);
        acc1 = MFMA(a1h, wq[ki], acc1, 0,0,0);
      }
      #pragma unroll
      for (int r=0; r<4; ++r){
        zs[wv][(lane>>4)*4 + r][l15]      = acc0[r];
        zs[wv][16 + (lane>>4)*4 + r][l15] = acc1[r];
      }
      __syncthreads();
      {
        int b = tid>>4, c = tid&15;
        float v = 0.f;
        #pragma unroll
        for (int w=0; w<8; ++w) v += zs[w][b][c];
        bstoref(&p.qf[b*NU + nq0 + c], v);           // bypass exchange
      }
      post(myflag, g2);
    }
    waitall(flags, g2, 64);
    // ---- phase C1: own 16 score rows (keys in registers) ----
    {
      uint4 qb[4];
      issue4q((const unsigned*)(p.qf + cb*NU + lane*16), qb);
      WAITC("0");
      float qr[16];
      #pragma unroll
      for (int j=0; j<4; ++j){
        qr[j*4+0] = __uint_as_float(qb[j].x);
        qr[j*4+1] = __uint_as_float(qb[j].y);
        qr[j*4+2] = __uint_as_float(qb[j].z);
        qr[j*4+3] = __uint_as_float(qb[j].w);
      }
      #pragma unroll
      for (int si=0; si<2; ++si){
        float pv = 0.f;
        #pragma unroll
        for (int j=0; j<8; ++j) pv += vr[j]   * tanh_(b2f(kr[si][0][j]) + qr[j]);
        #pragma unroll
        for (int j=0; j<8; ++j) pv += vr[8+j] * tanh_(b2f(kr[si][1][j]) + qr[8+j]);
        #pragma unroll
        for (int off=32; off; off>>=1) pv += __shfl_xor(pv, off);
        if (lane==0) bstoref(&p.scf[cb*128 + s0 + wv*2 + si], pv);
      }
    }
    post(myflag, g3);
    waitsib(flags, g3, sibbase);
    // ---- phase C2: softmax + ctx chunk (aB in registers) ----
    {
      float* alig = smem;          // [128]
      float* psum = smem + 128;    // [8][128]
      float* scl  = smem + 1280;   // [128]
      if (tid < 32){
        uint4 sv = bload4((const unsigned*)(p.scf + cb*128) + tid*4);
        *(uint4*)&scl[tid*4] = sv;
      }
      __syncthreads();
      if (tid < 64){
        float sA = scl[tid], sB = scl[64 + tid];
        float m = fmaxf(sA, sB);
        #pragma unroll
        for (int off=32; off; off>>=1) m = fmaxf(m, __shfl_xor(m, off));
        float e0 = __expf(sA-m), e1 = __expf(sB-m);
        float sum = e0+e1;
        #pragma unroll
        for (int off=32; off; off>>=1) sum += __shfl_xor(sum, off);
        float inv = frcp(sum);
        alig[tid] = e0*inv; alig[tid+64] = e1*inv;
      }
      __syncthreads();
      {
        float ax = 0.f, ay = 0.f;
        #pragma unroll
        for (int si=0; si<16; ++si){
          unsigned kv = av[si];
          float al = alig[sq8*16 + si];
          ax += al*b2f((u16)(kv & 0xffffu));
          ay += al*b2f((u16)(kv >> 16));
        }
        psum[sq8*128 + cp]   = ax;
        psum[sq8*128 + cp+1] = ay;
      }
      __syncthreads();
      if (tid < 128){
        float v = 0.f;
        #pragma unroll
        for (int s8=0; s8<8; ++s8) v += psum[s8*128 + tid];
        int col = c0 + tid, ci = cb*NU + col;
        u16 hi = f2b(v), lo = f2b(v - b2f(hi));
        bstore(&p.ctxPk[ci], ((unsigned)hi<<16)|lo);       // bypass exchange
        size_t ho = (size_t)(cb*NT + t)*2048 + 1024 + col;
        p.hcH[ho] = hi; p.hcL[ho] = lo;                    // history, cached
      }
    }
    post(myflag, g4);
    waitall(flags, g4, 256);
    hpPk = hoPk;
  }
}

// ---------------- logits: 128x128-tile, BK=64, double-buffered reg-staged ----------------
#define LDSK 72
__global__ __launch_bounds__(256) void k_logits(
    const u16* __restrict__ A,   // [4096][1024]
    const u16* __restrict__ Bt,  // [32000][1024]
    const float* __restrict__ bias,
    float* __restrict__ C)
{
  __shared__ __align__(16) u16 As[128*LDSK];
  __shared__ __align__(16) u16 Bs[128*LDSK];
  int tid = threadIdx.x, lane = tid&63, wv = tid>>6;
  int m0 = blockIdx.y*128, n0 = blockIdx.x*128;
  int wr = (wv>>1)*64, wc = (wv&1)*64;
  int l15 = lane&15, ko = (lane>>4)*8;
  int srow = tid>>3, sc8 = (tid&7)*8;
  f32x4 acc[4][4] = {};
  uint4 a0[4], b0[4], a1[4], b1[4];

  #define LOADG(ar, br, kk) { \
    _Pragma("unroll") \
    for (int i=0;i<4;++i){ \
      ar[i] = *(const uint4*)(A  + (size_t)(m0+srow+i*32)*1024 + (kk) + sc8); \
      br[i] = *(const uint4*)(Bt + (size_t)(n0+srow+i*32)*1024 + (kk) + sc8); \
    } }
  #define STORES(ar, br) { \
    _Pragma("unroll") \
    for (int i=0;i<4;++i){ \
      *(uint4*)(&As[(srow+i*32)*LDSK + sc8]) = ar[i]; \
      *(uint4*)(&Bs[(srow+i*32)*LDSK + sc8]) = br[i]; \
    } }
  #define COMPUTE() { \
    _Pragma("unroll") \
    for (int ks=0; ks<2; ++ks){ \
      bf16x8 af[4], bf[4]; \
      _Pragma("unroll") \
      for (int i=0;i<4;++i){ \
        af[i] = *(const bf16x8*)(&As[(wr+i*16+l15)*LDSK + ks*32 + ko]); \
        bf[i] = *(const bf16x8*)(&Bs[(wc+i*16+l15)*LDSK + ks*32 + ko]); \
      } \
      _Pragma("unroll") \
      for (int mi=0;mi<4;++mi) \
        _Pragma("unroll") \
        for (int ni=0;ni<4;++ni) \
          acc[mi][ni] = MFMA(af[mi], bf[ni], acc[mi][ni], 0,0,0); \
    } }

  LOADG(a0, b0, 0);
  for (int kk=0; kk<1024; kk+=128){
    __syncthreads();
    STORES(a0, b0);
    if (kk+64 < 1024) LOADG(a1, b1, kk+64);
    __syncthreads();
    COMPUTE();
    __syncthreads();
    STORES(a1, b1);
    if (kk+128 < 1024) LOADG(a0, b0, kk+128);
    __syncthreads();
    COMPUTE();
  }
  #pragma unroll
  for (int mi=0; mi<4; ++mi){
    int row = m0 + wr + mi*16 + (lane>>4)*4;
    #pragma unroll
    for (int ni=0; ni<4; ++ni){
      int col = n0 + wc + ni*16 + l15;
      float bval = bias[col];
      #pragma unroll
      for (int r=0; r<4; ++r){
        if (row + r < NB*NT)
          C[(size_t)(row+r)*NV + col] = acc[mi][ni][r] + bval;
      }
    }
  }
  #undef LOADG
  #undef STORES
  #undef COMPUTE
}

// ---------------- host ----------------
extern "C" void kernel_launch(void* const* d_in, const int* in_sizes, int n_in,
                              void* d_out, int out_size, void* d_ws, size_t ws_size,
                              hipStream_t stream)
{
  (void)in_sizes; (void)n_in; (void)out_size; (void)ws_size;
  const int*   toks  = (const int*)  d_in[0];
  const float* a_in  = (const float*)d_in[1];
  const float* a_tx  = (const float*)d_in[2];
  const float* c_tx  = (const float*)d_in[3];
  const float* emb   = (const float*)d_in[4];
  const float* W_k   = (const float*)d_in[5];
  const float* W_r   = (const float*)d_in[6];
  const float* bvec  = (const float*)d_in[7];
  const float* W_m   = (const float*)d_in[8];
  const float* W_q   = (const float*)d_in[9];
  const float* v_att = (const float*)d_in[10];
  const float* W_a   = (const float*)d_in[11];
  const float* W_o   = (const float*)d_in[12];
  const float* b_o   = (const float*)d_in[13];
  float* out = (float*)d_out;

  char* p = (char*)d_ws;
  auto alloc = [&](size_t bytes)->char*{ char* r = p; p += (bytes + 255) & ~(size_t)255; return r; };

  u16* WzhTH = (u16*)alloc((size_t)4096*1024*2);
  u16* WzhTL = (u16*)alloc((size_t)4096*1024*2);
  u16* WzcTH = (u16*)alloc((size_t)4096*1024*2);
  u16* WzcTL = (u16*)alloc((size_t)4096*1024*2);
  u16* Wr0TH = (u16*)alloc((size_t)4096*1024*2);   // reused as outsH after persist
  u16* Wr0TL = (u16*)alloc((size_t)4096*1024*2);
  u16* WqT   = (u16*)alloc((size_t)1024*1024*2);
  u16* WaTH  = (u16*)alloc((size_t)1024*2048*2);
  u16* WaTL  = (u16*)alloc((size_t)1024*2048*2);
  u16* WmT   = (u16*)alloc((size_t)1024*1024*2);
  u16* WoT   = (u16*)alloc((size_t)NV*1024*2);
  u16* WkxT  = (u16*)alloc((size_t)4096*256*2);
  u16* xB    = (u16*)alloc((size_t)4096*256*2);
  u16* xWb   = (u16*)alloc((size_t)4096*4096*2);
  u16* aB    = (u16*)alloc((size_t)4096*1024*2);
  u16* keysB = (u16*)alloc((size_t)4096*1024*2);
  // union region: prep { WkaT h/l, WaRow h/l, tmpF } -> persist { hcH, hcL }
  char* uni  = alloc((size_t)44*1024*1024);
  u16* WkaTH  = (u16*)uni;
  u16* WkaTL  = WkaTH + (size_t)4096*1024;
  u16* WaRowH = WkaTL + (size_t)4096*1024;
  u16* WaRowL = WaRowH + (size_t)2048*1024;
  float* tmpF = (float*)(WaRowL + (size_t)2048*1024);
  u16* hcH = (u16*)uni;
  u16* hcL = hcH + (size_t)4096*2048;

  unsigned* h0pk  = (unsigned*)alloc((size_t)NB*NU*4);
  unsigned* hPk0  = (unsigned*)alloc((size_t)NB*NU*4);
  unsigned* hPk1  = (unsigned*)alloc((size_t)NB*NU*4);
  unsigned* ctxPk = (unsigned*)alloc((size_t)NB*NU*4);
  float* qf   = (float*)alloc((size_t)NB*NU*4);
  float* scf  = (float*)alloc((size_t)NB*128*4);
  unsigned* flags = (unsigned*)alloc(4096);
  u16* outsH = Wr0TH;   // overlap (Wr0T dead after persist prologue)

  // ---- init ----
  (void)hipMemsetAsync(flags, 0, 4096, stream);
  (void)hipMemsetAsync(ctxPk, 0, (size_t)NB*NU*4, stream);
  k_pack<<<128,256,0,stream>>>(a_tx, h0pk, NB*NU);
  k_split<<<2048,256,0,stream>>>(W_a, WaRowH, WaRowL, 2048*1024);
  k_gather<<<(NB*NT*NE)/256,256,0,stream>>>(toks, emb, xB);
  k_conv<<<2048,256,0,stream>>>(a_in, aB, NB*128*NU);

  // ---- weight transposes ----
  k_transpose<<<dim3(128,32),256,0,stream>>>(W_k + (size_t)256*4096, 4096, WkaTH, WkaTL, 1024, 0);
  k_transpose<<<dim3(128,32),256,0,stream>>>(W_r, 4096, Wr0TH, Wr0TL, 1024, 0);
  k_transpose<<<dim3(32,32),256,0,stream>>>(W_q, 1024, WqT, nullptr, 1024, 0);
  k_transpose<<<dim3(32,64),256,0,stream>>>(W_a, 1024, WaTH, WaTL, 2048, 0);
  k_transpose<<<dim3(32,32),256,0,stream>>>(W_m, 1024, WmT, nullptr, 1024, 0);
  k_transpose<<<dim3(1000,32),256,0,stream>>>(W_o, NV, WoT, nullptr, 1024, 0);
  k_transpose<<<dim3(128,8),256,0,stream>>>(W_k, 4096, WkxT, nullptr, 256, 0);

  // ---- precompute GEMMs ----
  // keys = a @ W_m
  k_gemm64<1,0><<<dim3(16,64),256,0,stream>>>(aB, 1024, WmT, 1024, nullptr, keysB, 1024, nullptr, 4096, 1024);
  // xW = x @ W_k[0:256] + b
  k_gemm64<1,1><<<dim3(64,64),256,0,stream>>>(xB, 256, WkxT, 256, nullptr, xWb, 4096, bvec, NB*NT, 256);
  // Wzh = W_r + W_a[0:1024] @ Wk_attn  (3-term split, f32, then transpose+split)
  k_gemm128s<0><<<dim3(32,8),256,0,stream>>>(WaRowH, WaRowL, 1024, WkaTH, WkaTL, 1024,
                                             tmpF, nullptr, 4096, 1024, 1024);
  k_fuseT<<<dim3(128,32),256,0,stream>>>(tmpF, W_r, WzhTH, WzhTL);
  // Wzc = W_a[1024:2048] @ Wk_attn
  k_gemm128s<0><<<dim3(32,8),256,0,stream>>>(WaRowH + (size_t)1024*1024, WaRowL + (size_t)1024*1024, 1024,
                                             WkaTH, WkaTL, 1024, tmpF, nullptr, 4096, 1024, 1024);
  k_fuseT<<<dim3(128,32),256,0,stream>>>(tmpF, nullptr, WzcTH, WzcTL);

  // ---- persistent recurrence ----
  PP pp;
  pp.WzhTH=WzhTH; pp.WzhTL=WzhTL; pp.WzcTH=WzcTH; pp.WzcTL=WzcTL;
  pp.Wr0TH=Wr0TH; pp.Wr0TL=Wr0TL; pp.WqT=WqT; pp.xW=xWb;
  pp.keys=keysB; pp.aB=aB; pp.v_att=v_att; pp.c0f=c_tx;
  pp.h0pk=h0pk; pp.hPk0=hPk0; pp.hPk1=hPk1; pp.ctxPk=ctxPk;
  pp.qf=qf; pp.scf=scf;
  pp.hcH=hcH; pp.hcL=hcL; pp.flags=flags;
  k_persist<<<NBLK,512,0,stream>>>(pp);

  // ---- outs = [h|ctx] @ W_a  (3-term split, bf16 out, 128-tile) ----
  k_gemm128s<1><<<dim3(8,32),256,0,stream>>>(hcH, hcL, 2048, WaTH, WaTL, 2048,
                                             nullptr, outsH, 1024, NB*NT, 2048);

  // ---- logits = outs @ W_o + b_o ----
  k_logits<<<dim3(NV/128, 32),256,0,stream>>>(outsH, WoT, b_o, out);
}

// Round 13
// 5355.714 us; speedup vs baseline: 1.1309x; 1.0353x over previous
//
#include <hip/hip_runtime.h>
#include <cstdint>

#define DEVI __device__ __forceinline__

typedef unsigned short u16;
typedef __bf16 bf16x8 __attribute__((ext_vector_type(8)));
typedef u16 u16x8 __attribute__((ext_vector_type(8)));
typedef float f32x4 __attribute__((ext_vector_type(4)));

// B=32, T=128 (127 decode steps), V=32000, E=256, U=AU=M=1024, S=128
#define NB 32
#define NT 127
#define NV 32000
#define NE 256
#define NU 1024
#define NBLK 256
#define ROLLSTEP 65536   // 32*2048 u32 per step slot

DEVI float b2f(u16 h){ union{unsigned u; float f;} v; v.u = ((unsigned)h)<<16; return v.f; }
DEVI u16 f2b(float f){ union{float f; unsigned u;} v; v.f=f; unsigned u=v.u;
                       return (u16)((u + 0x7fffu + ((u>>16)&1u))>>16); }
DEVI float frcp(float x){ return __builtin_amdgcn_rcpf(x); }
DEVI float sigm(float x){ return frcp(1.f+__expf(-x)); }
DEVI float tanh_(float x){ return 1.f - 2.f*frcp(1.f+__expf(2.f*x)); }
#define MFMA __builtin_amdgcn_mfma_f32_16x16x32_bf16

// ---- coherent-bypass stores (sc0 sc1) and flag loads ----
DEVI void bstore(unsigned* p, unsigned v){
  asm volatile("global_store_dword %0, %1, off sc0 sc1" :: "v"(p), "v"(v) : "memory");
}
DEVI void bstoref(float* p, float v){
  asm volatile("global_store_dword %0, %1, off sc0 sc1" :: "v"(p), "v"(v) : "memory");
}
DEVI uint4 bload4(const unsigned* p){
  uint4 f;
  asm volatile("global_load_dwordx4 %0, %1, off sc0 sc1\n\ts_waitcnt vmcnt(0)"
               : "=v"(f) : "v"(p) : "memory");
  return f;
}
DEVI unsigned bload1(const unsigned* p){
  unsigned f;
  asm volatile("global_load_dword %0, %1, off sc0 sc1\n\ts_waitcnt vmcnt(0)"
               : "=v"(f) : "v"(p) : "memory");
  return f;
}
// unpack 8 packed words (hi<<16|lo) -> hi/lo bf16x8
DEVI void unpack8(uint4 x, uint4 y, bf16x8& ah, bf16x8& al){
  union { unsigned u[4]; bf16x8 v; } H, L;
  H.u[0] = (x.y & 0xffff0000u) | (x.x >> 16);
  L.u[0] = (x.y << 16)         | (x.x & 0xffffu);
  H.u[1] = (x.w & 0xffff0000u) | (x.z >> 16);
  L.u[1] = (x.w << 16)         | (x.z & 0xffffu);
  H.u[2] = (y.y & 0xffff0000u) | (y.x >> 16);
  L.u[2] = (y.y << 16)         | (y.x & 0xffffu);
  H.u[3] = (y.w & 0xffff0000u) | (y.z >> 16);
  L.u[3] = (y.w << 16)         | (y.z & 0xffffu);
  ah = H.v; al = L.v;
}

// ---------------- small conversion kernels ----------------
__global__ void k_conv(const float* __restrict__ s, u16* __restrict__ d, int n){
  for (int i = blockIdx.x*256 + threadIdx.x; i < n; i += gridDim.x*256) d[i] = f2b(s[i]);
}
__global__ void k_split(const float* __restrict__ s, u16* __restrict__ dh, u16* __restrict__ dl, int n){
  for (int i = blockIdx.x*256 + threadIdx.x; i < n; i += gridDim.x*256){
    float v = s[i]; u16 hi = f2b(v); dh[i]=hi; dl[i]=f2b(v-b2f(hi));
  }
}
// pack h0 [32][1024] f32 into roll slot 0 rows [b][0..1024)
__global__ void k_pack0(const float* __restrict__ s, unsigned* __restrict__ d){
  int i = blockIdx.x*256 + threadIdx.x;
  if (i >= NB*NU) return;
  float v = s[i]; u16 hi = f2b(v); u16 lo = f2b(v-b2f(hi));
  d[(i>>10)*2048 + (i&1023)] = ((unsigned)hi<<16)|lo;
}
__global__ void k_gather(const int* __restrict__ toks, const float* __restrict__ emb, u16* __restrict__ x){
  int i = blockIdx.x*256 + threadIdx.x;
  if (i >= NB*NT*NE) return;
  int bt = i>>8, e = i&255;
  int b = bt/NT, t = bt - b*NT;
  int tok = toks[b*128 + t];                 // dec_in = output_batch[:, :-1]
  x[i] = f2b(emb[(size_t)tok*NE + e]);
}
// transpose f32 (R x C, row stride rs) -> bf16 hi/lo (C x dstStride) at dst[c*dstStride+dstOff+r]
__global__ void k_transpose(const float* __restrict__ src, int rs,
                            u16* __restrict__ dh, u16* __restrict__ dl,
                            int dstStride, int dstOff){
  __shared__ float tile[32][33];
  int tc = blockIdx.x*32, tr = blockIdx.y*32;
  int tx = threadIdx.x & 31, ty = threadIdx.x >> 5;
  #pragma unroll
  for (int rr=0; rr<4; ++rr){
    int r = ty + rr*8;
    tile[r][tx] = src[(size_t)(tr+r)*rs + tc + tx];
  }
  __syncthreads();
  #pragma unroll
  for (int rr=0; rr<4; ++rr){
    int cl = ty + rr*8;
    float v = tile[tx][cl];
    u16 hi = f2b(v);
    size_t o = (size_t)(tc+cl)*dstStride + dstOff + tr + tx;
    dh[o] = hi;
    if (dl) dl[o] = f2b(v - b2f(hi));
  }
}
// transpose+add f32 C[1024][4096] (+addS) -> bf16 hi/lo dst[4096][1024]
__global__ void k_fuseT(const float* __restrict__ C, const float* __restrict__ addS,
                        u16* __restrict__ dh, u16* __restrict__ dl){
  __shared__ float tile[32][33];
  int tc = blockIdx.x*32, tr = blockIdx.y*32;
  int tx = threadIdx.x & 31, ty = threadIdx.x >> 5;
  #pragma unroll
  for (int rr=0; rr<4; ++rr){
    int r = ty + rr*8;
    float v = C[(size_t)(tr+r)*4096 + tc + tx];
    if (addS) v += addS[(size_t)(tr+r)*4096 + tc + tx];
    tile[r][tx] = v;
  }
  __syncthreads();
  #pragma unroll
  for (int rr=0; rr<4; ++rr){
    int cl = ty + rr*8;
    float v = tile[tx][cl];
    u16 hi = f2b(v);
    size_t o = (size_t)(tc+cl)*1024 + tr + tx;
    dh[o] = hi; dl[o] = f2b(v - b2f(hi));
  }
}

// ---------------- generic 64x64-tile bf16 MFMA GEMM (single-term) ----------------
template<int OUTF, int BIAS>
__global__ __launch_bounds__(256) void k_gemm64(
    const u16* __restrict__ A, int lda,
    const u16* __restrict__ Bt, int ldb,
    float* __restrict__ Cf, u16* __restrict__ Cb, int ldc,
    const float* __restrict__ bias, int M, int K)
{
  __shared__ __align__(16) u16 As[64][40];
  __shared__ __align__(16) u16 Bs[64][40];
  int n0 = blockIdx.x*64, m0 = blockIdx.y*64;
  int tid = threadIdx.x, lane = tid & 63, w = tid>>6;
  int lr = tid>>2, lk = (tid&3)*8;
  f32x4 acc[4] = {};
  for (int kk=0; kk<K; kk+=32){
    uint4 av = make_uint4(0,0,0,0);
    int row = m0 + lr;
    if (row < M) av = *(const uint4*)(A + (size_t)row*lda + kk + lk);
    *(uint4*)(&As[lr][lk]) = av;
    uint4 bv = *(const uint4*)(Bt + (size_t)(n0+lr)*ldb + kk + lk);
    *(uint4*)(&Bs[lr][lk]) = bv;
    __syncthreads();
    bf16x8 af = *(const bf16x8*)(&As[w*16 + (lane&15)][(lane>>4)*8]);
    #pragma unroll
    for (int ni=0; ni<4; ++ni){
      bf16x8 bfr = *(const bf16x8*)(&Bs[ni*16 + (lane&15)][(lane>>4)*8]);
      acc[ni] = MFMA(af, bfr, acc[ni], 0,0,0);
    }
    __syncthreads();
  }
  #pragma unroll
  for (int ni=0; ni<4; ++ni){
    #pragma unroll
    for (int r=0; r<4; ++r){
      int row = m0 + w*16 + (lane>>4)*4 + r;
      int col = n0 + ni*16 + (lane&15);
      if (row < M){
        float v = acc[ni][r];
        if (BIAS) v += bias[col];
        if (OUTF==0) Cf[(size_t)row*ldc + col] = v;
        else         Cb[(size_t)row*ldc + col] = f2b(v);
      }
    }
  }
}

// ------- 128x128-tile, BK=32, 3-term split GEMM: (Ah+Al) x (Bh+Bl), N mult of 128 -------
template<int OUTF>
__global__ __launch_bounds__(256) void k_gemm128s(
    const u16* __restrict__ Ah, const u16* __restrict__ Al, int lda,
    const u16* __restrict__ Bh, const u16* __restrict__ Bl, int ldb,
    float* __restrict__ Cf, u16* __restrict__ Cb, int ldc, int M, int K)
{
  __shared__ __align__(16) u16 AsH[128][40], AsL[128][40], BsH[128][40], BsL[128][40];
  int n0 = blockIdx.x*128, m0 = blockIdx.y*128;
  int tid = threadIdx.x, lane = tid&63, wv = tid>>6;
  int lr = tid>>1, lk = (tid&1)*16;
  int wr = (wv>>1)*64, wc = (wv&1)*64;
  int l15 = lane&15, ko = (lane>>4)*8;
  f32x4 acc[4][4] = {};
  for (int kk=0; kk<K; kk+=32){
    uint4 z = make_uint4(0,0,0,0);
    uint4 ah0=z, ah1=z, al0=z, al1=z;
    int row = m0 + lr;
    if (row < M){
      ah0 = *(const uint4*)(Ah + (size_t)row*lda + kk + lk);
      ah1 = *(const uint4*)(Ah + (size_t)row*lda + kk + lk + 8);
      al0 = *(const uint4*)(Al + (size_t)row*lda + kk + lk);
      al1 = *(const uint4*)(Al + (size_t)row*lda + kk + lk + 8);
    }
    *(uint4*)&AsH[lr][lk]   = ah0;
    *(uint4*)&AsH[lr][lk+8] = ah1;
    *(uint4*)&AsL[lr][lk]   = al0;
    *(uint4*)&AsL[lr][lk+8] = al1;
    *(uint4*)&BsH[lr][lk]   = *(const uint4*)(Bh + (size_t)(n0+lr)*ldb + kk + lk);
    *(uint4*)&BsH[lr][lk+8] = *(const uint4*)(Bh + (size_t)(n0+lr)*ldb + kk + lk + 8);
    *(uint4*)&BsL[lr][lk]   = *(const uint4*)(Bl + (size_t)(n0+lr)*ldb + kk + lk);
    *(uint4*)&BsL[lr][lk+8] = *(const uint4*)(Bl + (size_t)(n0+lr)*ldb + kk + lk + 8);
    __syncthreads();
    bf16x8 afh[4], afl[4], bfh[4], bfl[4];
    #pragma unroll
    for (int i=0;i<4;++i){
      afh[i] = *(const bf16x8*)&AsH[wr+i*16+l15][ko];
      afl[i] = *(const bf16x8*)&AsL[wr+i*16+l15][ko];
      bfh[i] = *(const bf16x8*)&BsH[wc+i*16+l15][ko];
      bfl[i] = *(const bf16x8*)&BsL[wc+i*16+l15][ko];
    }
    #pragma unroll
    for (int mi=0;mi<4;++mi)
      #pragma unroll
      for (int ni=0;ni<4;++ni){
        acc[mi][ni] = MFMA(afh[mi], bfl[ni], acc[mi][ni], 0,0,0);
        acc[mi][ni] = MFMA(afl[mi], bfh[ni], acc[mi][ni], 0,0,0);
        acc[mi][ni] = MFMA(afh[mi], bfh[ni], acc[mi][ni], 0,0,0);
      }
    __syncthreads();
  }
  #pragma unroll
  for (int mi=0;mi<4;++mi){
    int rowb = m0 + wr + mi*16 + (lane>>4)*4;
    #pragma unroll
    for (int ni=0;ni<4;++ni){
      int col = n0 + wc + ni*16 + l15;
      #pragma unroll
      for (int r=0;r<4;++r){
        if (rowb + r < M){
          float v = acc[mi][ni][r];
          if (OUTF==0) Cf[(size_t)(rowb+r)*ldc + col] = v;
          else         Cb[(size_t)(rowb+r)*ldc + col] = f2b(v);
        }
      }
    }
  }
}

// ---------------- persistent recurrence kernel ----------------
struct PP {
  const u16 *WzhTH, *WzhTL;   // [4096][1024]
  const u16 *WzcTH, *WzcTL;   // [4096][1024]
  const u16 *Wr0TH, *Wr0TL;   // [4096][1024] (t=0 h-weight = W_r^T)
  const u16 *WqT;             // [1024][1024]
  const u16 *xW;              // rows b*NT+t, 4096 cols (bf16, bias folded)
  const u16 *keys;            // [4096][1024]
  const u16 *aB;              // [4096][1024]
  const float *v_att;         // [1024]
  const float *c0f;           // [32][1024] initial c (f32)
  unsigned *roll;             // [(NT+1)][32][2048] packed h|ctx — write-once rolling
  float *qroll;               // [NT][32][1024] — write-once rolling
  float *scroll;              // [NT][32][128] — write-once rolling
  u16 *hcH, *hcL;             // [4096][2048] hist [h | ctx] cached (read post-kernel)
  unsigned *flags;            // [256] per-block generation flags (no atomics!)
};

// zero-RMW barrier: post own flag (plain bypass store), poll flags wide w/ backoff.
DEVI void post(unsigned* myflag, unsigned gen){
  asm volatile("s_waitcnt vmcnt(0)" ::: "memory");   // per-wave: all stores committed
  __syncthreads();                                    // whole block drained
  if (threadIdx.x == 0) bstore(myflag, gen);
}
// wait until flags[0..nflags) >= gen. Wave 0 polls: lane i checks flags[4i..4i+3].
DEVI void waitall(const unsigned* flags, unsigned gen, int nflags){
  if (threadIdx.x < 64){
    int idx = (int)threadIdx.x * 4;
    bool active = idx < nflags;
    const unsigned* fp = flags + (active ? idx : 0);
    for (;;){
      uint4 f = bload4(fp);
      bool ok = !active || (f.x>=gen && f.y>=gen && f.z>=gen && f.w>=gen);
      if (__all(ok)) break;
      __builtin_amdgcn_s_sleep(4);
    }
  }
  __syncthreads();
}
// wait until the 8 sibling flags (base + 8j) >= gen (narrow poll, lanes 0..7)
DEVI void waitsib(const unsigned* flags, unsigned gen, int base){
  if (threadIdx.x < 8){
    const unsigned* fp = flags + base + ((int)threadIdx.x << 3);
    for (;;){
      unsigned f = bload1(fp);
      if (__all(f >= gen)) break;
      __builtin_amdgcn_s_sleep(2);
    }
  }
  __syncthreads();
}

__global__ __launch_bounds__(512,1) void k_persist(PP p){
  __shared__ float smem[4096];   // zs[8][32][16] | C2: alig[128]+psum[8][128]+scl[128]
  float (*zs)[32][16] = (float(*)[32][16])smem;
  int tid = threadIdx.x, lane = tid&63, wv = tid>>6, blk = blockIdx.x;
  int l15 = lane&15, ko = (lane>>4)*8;
  unsigned* flags = p.flags;
  unsigned* myflag = flags + blk;

  // ============ register preloads (cached RO, never invalidated — no fences) =========
  int u0 = blk*4;
  int wrow = (l15>>2)*1024 + u0 + (l15&3);
  size_t woff = (size_t)wrow*1024 + (wv&3)*256 + ko;
  const u16 *whG = (wv<4 ? p.Wr0TH : p.WzcTH) + woff;
  const u16 *wlG = (wv<4 ? p.Wr0TL : p.WzcTL) + woff;
  bf16x8 wH[8], wL[8];
  #pragma unroll
  for (int ki=0; ki<8; ++ki){
    wH[ki] = *(const bf16x8*)(whG + ki*32);
    wL[ki] = *(const bf16x8*)(wlG + ki*32);
  }
  bf16x8 wq[4];
  int nq0 = (blk&63)*16;
  if (blk < 64){
    const u16* qg = p.WqT + (size_t)(nq0+l15)*1024 + wv*128 + ko;
    #pragma unroll
    for (int ki=0; ki<4; ++ki) wq[ki] = *(const bf16x8*)(qg + ki*32);
  }
  // block-private LSTM cell state (register-resident)
  float creg = 0.f;
  if (tid < 128) creg = p.c0f[(tid>>2)*NU + u0 + (tid&3)];
  // phase-C mapping: co-locate a batch's 8 blocks on one XCD (XCD = blk%8)
  int m8 = blk>>3;
  int cb = (blk&7)*4 + (m8>>3);     // batch 0..31
  int c0 = (m8&7)*128;              // ctx col chunk
  int s0 = (m8&7)*16;               // score row chunk (C1)
  int sibbase = (blk&7) + 64*(blk>>6);  // siblings: sibbase + 8j, j=0..7
  int cp = 2*(tid&63), sq8 = tid>>6;
  unsigned av[16];
  #pragma unroll
  for (int si=0; si<16; ++si)
    av[si] = *(const unsigned*)(p.aB + (size_t)(cb*128 + sq8*16 + si)*1024 + c0 + cp);
  // keys slice for C1 (rows s0+wv*2+{0,1}) — register-pinned
  u16x8 kr[2][2];
  #pragma unroll
  for (int si=0; si<2; ++si){
    const u16* kp = p.keys + (size_t)(cb*128 + s0 + wv*2 + si)*1024 + lane*16;
    kr[si][0] = *(const u16x8*)kp;
    kr[si][1] = *(const u16x8*)(kp + 8);
  }
  // v_att slice (loop-invariant)
  float vr[16];
  #pragma unroll
  for (int j=0; j<4; ++j)
    *(float4*)&vr[j*4] = *(const float4*)(p.v_att + lane*16 + j*4);

  for (int t=0; t<NT; ++t){
    unsigned g1 = 4u*t + 1u, g2 = 4u*t + 2u, g3 = 4u*t + 3u, g4 = 4u*t + 4u;
    unsigned* rollW = p.roll + (size_t)(t+1)*ROLLSTEP;   // this step's outputs
    // ---- phase A: z = xW + h@Wzh + ctx@Wzc -> gates -> h,c ----
    {
      // xW gate biases (cached, hidden under load pipeline)
      float xw0=0.f, xw1=0.f, xw2=0.f, xw3=0.f;
      if (tid < 128){
        const u16* xw = p.xW + (size_t)((tid>>2)*NT + t)*4096 + u0 + (tid&3);
        xw0 = b2f(xw[0]); xw1 = b2f(xw[1024]); xw2 = b2f(xw[2048]); xw3 = b2f(xw[3072]);
      }
      // cached cold reads of [h|ctx] from roll[t] (write-once addresses => never stale)
      const unsigned* Apk = p.roll + (size_t)t*ROLLSTEP + (wv<4 ? 0 : 1024);
      int kb = (wv&3)*256;
      const unsigned* b0 = Apk + (size_t)l15*2048 + kb + ko;
      const unsigned* b1 = b0 + 16*2048;
      f32x4 acc0 = {}, acc1 = {};
      #pragma unroll
      for (int ki=0; ki<8; ++ki){
        uint4 x0 = *(const uint4*)(b0 + ki*32);
        uint4 y0 = *(const uint4*)(b0 + ki*32 + 4);
        uint4 x1 = *(const uint4*)(b1 + ki*32);
        uint4 y1 = *(const uint4*)(b1 + ki*32 + 4);
        bf16x8 a0h, a0l, a1h, a1l;
        unpack8(x0, y0, a0h, a0l);
        unpack8(x1, y1, a1h, a1l);
        acc0 = MFMA(a0h, wL[ki], acc0, 0,0,0);
        acc0 = MFMA(a0l, wH[ki], acc0, 0,0,0);
        acc0 = MFMA(a0h, wH[ki], acc0, 0,0,0);
        acc1 = MFMA(a1h, wL[ki], acc1, 0,0,0);
        acc1 = MFMA(a1l, wH[ki], acc1, 0,0,0);
        acc1 = MFMA(a1h, wH[ki], acc1, 0,0,0);
      }
      if (t == 0 && wv < 4){   // swap Wr0 -> steady-state Wzh (hidden under B/C)
        const u16* nh = p.WzhTH + woff;
        const u16* nl = p.WzhTL + woff;
        #pragma unroll
        for (int ki=0; ki<8; ++ki){
          wH[ki] = *(const bf16x8*)(nh + ki*32);
          wL[ki] = *(const bf16x8*)(nl + ki*32);
        }
      }
      #pragma unroll
      for (int r=0; r<4; ++r){
        zs[wv][(lane>>4)*4 + r][l15]      = acc0[r];
        zs[wv][16 + (lane>>4)*4 + r][l15] = acc1[r];
      }
      __syncthreads();
      if (tid < 128){
        int b = tid>>2, du = tid&3;
        float zg[4];
        #pragma unroll
        for (int g=0; g<4; ++g){
          float v = 0.f;
          #pragma unroll
          for (int w=0; w<8; ++w) v += zs[w][b][g*4+du];
          zg[g] = v;
        }
        zg[0] += xw0; zg[1] += xw1; zg[2] += xw2; zg[3] += xw3;
        float i_ = sigm(zg[0]), f_ = sigm(zg[1]), g_ = tanh_(zg[2]), o_ = sigm(zg[3]);
        float cn = f_*creg + i_*g_;
        creg = cn;
        float h = o_*tanh_(cn);
        u16 hi = f2b(h), lo = f2b(h - b2f(hi));
        bstore(&rollW[b*2048 + u0 + du], ((unsigned)hi<<16)|lo);  // bypass, write-once
        size_t ho = (size_t)(b*NT + t)*2048 + u0 + du;
        p.hcH[ho] = hi; p.hcL[ho] = lo;                           // history, cached
      }
    }
    post(myflag, g1);
    // ---- phase B: q = h@W_q (blocks 0..63) ----
    if (blk < 64){
      waitall(flags, g1, 256);
      // cached cold reads of h from roll[t+1] (first touch this launch)
      const unsigned* b0 = rollW + (size_t)l15*2048 + wv*128 + ko;
      const unsigned* b1 = b0 + 16*2048;
      f32x4 acc0 = {}, acc1 = {};
      #pragma unroll
      for (int ki=0; ki<4; ++ki){
        uint4 x0 = *(const uint4*)(b0 + ki*32);
        uint4 y0 = *(const uint4*)(b0 + ki*32 + 4);
        uint4 x1 = *(const uint4*)(b1 + ki*32);
        uint4 y1 = *(const uint4*)(b1 + ki*32 + 4);
        bf16x8 a0h, a0l, a1h, a1l;
        unpack8(x0, y0, a0h, a0l);
        unpack8(x1, y1, a1h, a1l);
        acc0 = MFMA(a0l, wq[ki], acc0, 0,0,0);
        acc0 = MFMA(a0h, wq[ki], acc0, 0,0,0);
        acc1 = MFMA(a1l, wq[ki], acc1, 0,0,0);
        acc1 = MFMA(a1h, wq[ki], acc1, 0,0,0);
      }
      #pragma unroll
      for (int r=0; r<4; ++r){
        zs[wv][(lane>>4)*4 + r][l15]      = acc0[r];
        zs[wv][16 + (lane>>4)*4 + r][l15] = acc1[r];
      }
      __syncthreads();
      {
        int b = tid>>4, c = tid&15;
        float v = 0.f;
        #pragma unroll
        for (int w=0; w<8; ++w) v += zs[w][b][c];
        bstoref(&p.qroll[(size_t)t*32768 + b*NU + nq0 + c], v);   // bypass, write-once
      }
      post(myflag, g2);
    }
    waitall(flags, g2, 64);
    // ---- phase C1: own 16 score rows (keys in registers; q cached cold) ----
    {
      const float* qp = p.qroll + (size_t)t*32768 + cb*NU + lane*16;
      float qr[16];
      #pragma unroll
      for (int j=0; j<4; ++j)
        *(float4*)&qr[j*4] = *(const float4*)(qp + j*4);
      #pragma unroll
      for (int si=0; si<2; ++si){
        float pv = 0.f;
        #pragma unroll
        for (int j=0; j<8; ++j) pv += vr[j]   * tanh_(b2f(kr[si][0][j]) + qr[j]);
        #pragma unroll
        for (int j=0; j<8; ++j) pv += vr[8+j] * tanh_(b2f(kr[si][1][j]) + qr[8+j]);
        #pragma unroll
        for (int off=32; off; off>>=1) pv += __shfl_xor(pv, off);
        if (lane==0) bstoref(&p.scroll[(size_t)t*4096 + cb*128 + s0 + wv*2 + si], pv);
      }
    }
    post(myflag, g3);
    waitsib(flags, g3, sibbase);
    // ---- phase C2: softmax + ctx chunk (aB in registers; scores cached cold) ----
    {
      float* alig = smem;          // [128]
      float* psum = smem + 128;    // [8][128]
      float* scl  = smem + 1280;   // [128]
      if (tid < 32)
        *(uint4*)&scl[tid*4] = ((const uint4*)(p.scroll + (size_t)t*4096 + cb*128))[tid];
      __syncthreads();
      if (tid < 64){
        float sA = scl[tid], sB = scl[64 + tid];
        float m = fmaxf(sA, sB);
        #pragma unroll
        for (int off=32; off; off>>=1) m = fmaxf(m, __shfl_xor(m, off));
        float e0 = __expf(sA-m), e1 = __expf(sB-m);
        float sum = e0+e1;
        #pragma unroll
        for (int off=32; off; off>>=1) sum += __shfl_xor(sum, off);
        float inv = frcp(sum);
        alig[tid] = e0*inv; alig[tid+64] = e1*inv;
      }
      __syncthreads();
      {
        float ax = 0.f, ay = 0.f;
        #pragma unroll
        for (int si=0; si<16; ++si){
          unsigned kv = av[si];
          float al = alig[sq8*16 + si];
          ax += al*b2f((u16)(kv & 0xffffu));
          ay += al*b2f((u16)(kv >> 16));
        }
        psum[sq8*128 + cp]   = ax;
        psum[sq8*128 + cp+1] = ay;
      }
      __syncthreads();
      if (tid < 128){
        float v = 0.f;
        #pragma unroll
        for (int s8=0; s8<8; ++s8) v += psum[s8*128 + tid];
        int col = c0 + tid;
        u16 hi = f2b(v), lo = f2b(v - b2f(hi));
        bstore(&rollW[cb*2048 + 1024 + col], ((unsigned)hi<<16)|lo);  // bypass, write-once
        size_t ho = (size_t)(cb*NT + t)*2048 + 1024 + col;
        p.hcH[ho] = hi; p.hcL[ho] = lo;                               // history, cached
      }
    }
    post(myflag, g4);
    waitall(flags, g4, 256);
  }
}

// ---------------- logits: 128x128-tile, BK=64, double-buffered reg-staged ----------------
#define LDSK 72
__global__ __launch_bounds__(256) void k_logits(
    const u16* __restrict__ A,   // [4096][1024]
    const u16* __restrict__ Bt,  // [32000][1024]
    const float* __restrict__ bias,
    float* __restrict__ C)
{
  __shared__ __align__(16) u16 As[128*LDSK];
  __shared__ __align__(16) u16 Bs[128*LDSK];
  int tid = threadIdx.x, lane = tid&63, wv = tid>>6;
  int m0 = blockIdx.y*128, n0 = blockIdx.x*128;
  int wr = (wv>>1)*64, wc = (wv&1)*64;
  int l15 = lane&15, ko = (lane>>4)*8;
  int srow = tid>>3, sc8 = (tid&7)*8;
  f32x4 acc[4][4] = {};
  uint4 a0[4], b0[4], a1[4], b1[4];

  #define LOADG(ar, br, kk) { \
    _Pragma("unroll") \
    for (int i=0;i<4;++i){ \
      ar[i] = *(const uint4*)(A  + (size_t)(m0+srow+i*32)*1024 + (kk) + sc8); \
      br[i] = *(const uint4*)(Bt + (size_t)(n0+srow+i*32)*1024 + (kk) + sc8); \
    } }
  #define STORES(ar, br) { \
    _Pragma("unroll") \
    for (int i=0;i<4;++i){ \
      *(uint4*)(&As[(srow+i*32)*LDSK + sc8]) = ar[i]; \
      *(uint4*)(&Bs[(srow+i*32)*LDSK + sc8]) = br[i]; \
    } }
  #define COMPUTE() { \
    _Pragma("unroll") \
    for (int ks=0; ks<2; ++ks){ \
      bf16x8 af[4], bf[4]; \
      _Pragma("unroll") \
      for (int i=0;i<4;++i){ \
        af[i] = *(const bf16x8*)(&As[(wr+i*16+l15)*LDSK + ks*32 + ko]); \
        bf[i] = *(const bf16x8*)(&Bs[(wc+i*16+l15)*LDSK + ks*32 + ko]); \
      } \
      _Pragma("unroll") \
      for (int mi=0;mi<4;++mi) \
        _Pragma("unroll") \
        for (int ni=0;ni<4;++ni) \
          acc[mi][ni] = MFMA(af[mi], bf[ni], acc[mi][ni], 0,0,0); \
    } }

  LOADG(a0, b0, 0);
  for (int kk=0; kk<1024; kk+=128){
    __syncthreads();
    STORES(a0, b0);
    if (kk+64 < 1024) LOADG(a1, b1, kk+64);
    __syncthreads();
    COMPUTE();
    __syncthreads();
    STORES(a1, b1);
    if (kk+128 < 1024) LOADG(a0, b0, kk+128);
    __syncthreads();
    COMPUTE();
  }
  #pragma unroll
  for (int mi=0; mi<4; ++mi){
    int row = m0 + wr + mi*16 + (lane>>4)*4;
    #pragma unroll
    for (int ni=0; ni<4; ++ni){
      int col = n0 + wc + ni*16 + l15;
      float bval = bias[col];
      #pragma unroll
      for (int r=0; r<4; ++r){
        if (row + r < NB*NT)
          C[(size_t)(row+r)*NV + col] = acc[mi][ni][r] + bval;
      }
    }
  }
  #undef LOADG
  #undef STORES
  #undef COMPUTE
}

// ---------------- host ----------------
extern "C" void kernel_launch(void* const* d_in, const int* in_sizes, int n_in,
                              void* d_out, int out_size, void* d_ws, size_t ws_size,
                              hipStream_t stream)
{
  (void)in_sizes; (void)n_in; (void)out_size; (void)ws_size;
  const int*   toks  = (const int*)  d_in[0];
  const float* a_in  = (const float*)d_in[1];
  const float* a_tx  = (const float*)d_in[2];
  const float* c_tx  = (const float*)d_in[3];
  const float* emb   = (const float*)d_in[4];
  const float* W_k   = (const float*)d_in[5];
  const float* W_r   = (const float*)d_in[6];
  const float* bvec  = (const float*)d_in[7];
  const float* W_m   = (const float*)d_in[8];
  const float* W_q   = (const float*)d_in[9];
  const float* v_att = (const float*)d_in[10];
  const float* W_a   = (const float*)d_in[11];
  const float* W_o   = (const float*)d_in[12];
  const float* b_o   = (const float*)d_in[13];
  float* out = (float*)d_out;

  char* p = (char*)d_ws;
  auto alloc = [&](size_t bytes)->char*{ char* r = p; p += (bytes + 255) & ~(size_t)255; return r; };

  u16* WzhTH = (u16*)alloc((size_t)4096*1024*2);
  u16* WzhTL = (u16*)alloc((size_t)4096*1024*2);
  u16* WzcTH = (u16*)alloc((size_t)4096*1024*2);
  u16* WzcTL = (u16*)alloc((size_t)4096*1024*2);
  u16* Wr0TH = (u16*)alloc((size_t)4096*1024*2);   // reused as outsH after persist
  u16* Wr0TL = (u16*)alloc((size_t)4096*1024*2);
  u16* WqT   = (u16*)alloc((size_t)1024*1024*2);
  u16* WaTH  = (u16*)alloc((size_t)1024*2048*2);
  u16* WaTL  = (u16*)alloc((size_t)1024*2048*2);
  u16* WmT   = (u16*)alloc((size_t)1024*1024*2);
  u16* WoT   = (u16*)alloc((size_t)NV*1024*2);
  u16* WkxT  = (u16*)alloc((size_t)4096*256*2);
  u16* xB    = (u16*)alloc((size_t)4096*256*2);
  u16* xWb   = (u16*)alloc((size_t)4096*4096*2);
  u16* aB    = (u16*)alloc((size_t)4096*1024*2);
  u16* keysB = (u16*)alloc((size_t)4096*1024*2);
  // union region: prep { WkaT h/l, WaRow h/l, tmpF } -> persist { hcH, hcL }
  char* uni  = alloc((size_t)44*1024*1024);
  u16* WkaTH  = (u16*)uni;
  u16* WkaTL  = WkaTH + (size_t)4096*1024;
  u16* WaRowH = WkaTL + (size_t)4096*1024;
  u16* WaRowL = WaRowH + (size_t)2048*1024;
  float* tmpF = (float*)(WaRowL + (size_t)2048*1024);
  u16* hcH = (u16*)uni;
  u16* hcL = hcH + (size_t)4096*2048;

  unsigned* roll   = (unsigned*)alloc((size_t)(NT+1)*ROLLSTEP*4);   // 33.6 MB
  float*    qroll  = (float*)alloc((size_t)NT*NB*NU*4);             // 16.6 MB
  float*    scroll = (float*)alloc((size_t)NT*NB*128*4);            // 2.1 MB
  unsigned* flags  = (unsigned*)alloc(4096);
  u16* outsH = Wr0TH;   // overlap (Wr0T dead after persist prologue)

  // ---- init ----
  (void)hipMemsetAsync(flags, 0, 4096, stream);
  (void)hipMemsetAsync(roll, 0, (size_t)ROLLSTEP*4, stream);   // slot 0 (ctx0 = 0)
  k_pack0<<<128,256,0,stream>>>(a_tx, roll);
  k_split<<<2048,256,0,stream>>>(W_a, WaRowH, WaRowL, 2048*1024);
  k_gather<<<(NB*NT*NE)/256,256,0,stream>>>(toks, emb, xB);
  k_conv<<<2048,256,0,stream>>>(a_in, aB, NB*128*NU);

  // ---- weight transposes ----
  k_transpose<<<dim3(128,32),256,0,stream>>>(W_k + (size_t)256*4096, 4096, WkaTH, WkaTL, 1024, 0);
  k_transpose<<<dim3(128,32),256,0,stream>>>(W_r, 4096, Wr0TH, Wr0TL, 1024, 0);
  k_transpose<<<dim3(32,32),256,0,stream>>>(W_q, 1024, WqT, nullptr, 1024, 0);
  k_transpose<<<dim3(32,64),256,0,stream>>>(W_a, 1024, WaTH, WaTL, 2048, 0);
  k_transpose<<<dim3(32,32),256,0,stream>>>(W_m, 1024, WmT, nullptr, 1024, 0);
  k_transpose<<<dim3(1000,32),256,0,stream>>>(W_o, NV, WoT, nullptr, 1024, 0);
  k_transpose<<<dim3(128,8),256,0,stream>>>(W_k, 4096, WkxT, nullptr, 256, 0);

  // ---- precompute GEMMs ----
  // keys = a @ W_m
  k_gemm64<1,0><<<dim3(16,64),256,0,stream>>>(aB, 1024, WmT, 1024, nullptr, keysB, 1024, nullptr, 4096, 1024);
  // xW = x @ W_k[0:256] + b
  k_gemm64<1,1><<<dim3(64,64),256,0,stream>>>(xB, 256, WkxT, 256, nullptr, xWb, 4096, bvec, NB*NT, 256);
  // Wzh = W_r + W_a[0:1024] @ Wk_attn  (3-term split, f32, then transpose+split)
  k_gemm128s<0><<<dim3(32,8),256,0,stream>>>(WaRowH, WaRowL, 1024, WkaTH, WkaTL, 1024,
                                             tmpF, nullptr, 4096, 1024, 1024);
  k_fuseT<<<dim3(128,32),256,0,stream>>>(tmpF, W_r, WzhTH, WzhTL);
  // Wzc = W_a[1024:2048] @ Wk_attn
  k_gemm128s<0><<<dim3(32,8),256,0,stream>>>(WaRowH + (size_t)1024*1024, WaRowL + (size_t)1024*1024, 1024,
                                             WkaTH, WkaTL, 1024, tmpF, nullptr, 4096, 1024, 1024);
  k_fuseT<<<dim3(128,32),256,0,stream>>>(tmpF, nullptr, WzcTH, WzcTL);

  // ---- persistent recurrence ----
  PP pp;
  pp.WzhTH=WzhTH; pp.WzhTL=WzhTL; pp.WzcTH=WzcTH; pp.WzcTL=WzcTL;
  pp.Wr0TH=Wr0TH; pp.Wr0TL=Wr0TL; pp.WqT=WqT; pp.xW=xWb;
  pp.keys=keysB; pp.aB=aB; pp.v_att=v_att; pp.c0f=c_tx;
  pp.roll=roll; pp.qroll=qroll; pp.scroll=scroll;
  pp.hcH=hcH; pp.hcL=hcL; pp.flags=flags;
  k_persist<<<NBLK,512,0,stream>>>(pp);

  // ---- outs = [h|ctx] @ W_a  (3-term split, bf16 out, 128-tile) ----
  k_gemm128s<1><<<dim3(8,32),256,0,stream>>>(hcH, hcL, 2048, WaTH, WaTL, 2048,
                                             nullptr, outsH, 1024, NB*NT, 2048);

  // ---- logits = outs @ W_o + b_o ----
  k_logits<<<dim3(NV/128, 32),256,0,stream>>>(outsH, WoT, b_o, out);
}

// Round 14
// 4994.126 us; speedup vs baseline: 1.2128x; 1.0724x over previous
//
#include <hip/hip_runtime.h>
#include <cstdint>

#define DEVI __device__ __forceinline__

typedef unsigned short u16;
typedef __bf16 bf16x8 __attribute__((ext_vector_type(8)));
typedef u16 u16x8 __attribute__((ext_vector_type(8)));
typedef float f32x4 __attribute__((ext_vector_type(4)));

// B=32, T=128 (127 decode steps), V=32000, E=256, U=AU=M=1024, S=128
#define NB 32
#define NT 127
#define NV 32000
#define NE 256
#define NU 1024
#define NBLK 256
#define ROLLSTEP 65536   // 32*2048 u32 per step slot
#define SENT 0xFFFFFFFFu

DEVI float b2f(u16 h){ union{unsigned u; float f;} v; v.u = ((unsigned)h)<<16; return v.f; }
DEVI u16 f2b(float f){ union{float f; unsigned u;} v; v.f=f; unsigned u=v.u;
                       return (u16)((u + 0x7fffu + ((u>>16)&1u))>>16); }
DEVI float frcp(float x){ return __builtin_amdgcn_rcpf(x); }
DEVI float sigm(float x){ return frcp(1.f+__expf(-x)); }
DEVI float tanh_(float x){ return 1.f - 2.f*frcp(1.f+__expf(2.f*x)); }
#define MFMA __builtin_amdgcn_mfma_f32_16x16x32_bf16

// ---- coherent-bypass stores (sc0 sc1) and poll loads ----
DEVI void bstore(unsigned* p, unsigned v){
  asm volatile("global_store_dword %0, %1, off sc0 sc1" :: "v"(p), "v"(v) : "memory");
}
DEVI void bstoref(float* p, float v){
  asm volatile("global_store_dword %0, %1, off sc0 sc1" :: "v"(p), "v"(v) : "memory");
}
DEVI uint4 bload4(const unsigned* p){
  uint4 f;
  asm volatile("global_load_dwordx4 %0, %1, off sc0 sc1\n\ts_waitcnt vmcnt(0)"
               : "=v"(f) : "v"(p) : "memory");
  return f;
}
// unpack 8 packed words (hi<<16|lo) -> hi/lo bf16x8
DEVI void unpack8(uint4 x, uint4 y, bf16x8& ah, bf16x8& al){
  union { unsigned u[4]; bf16x8 v; } H, L;
  H.u[0] = (x.y & 0xffff0000u) | (x.x >> 16);
  L.u[0] = (x.y << 16)         | (x.x & 0xffffu);
  H.u[1] = (x.w & 0xffff0000u) | (x.z >> 16);
  L.u[1] = (x.w << 16)         | (x.z & 0xffffu);
  H.u[2] = (y.y & 0xffff0000u) | (y.x >> 16);
  L.u[2] = (y.y << 16)         | (y.x & 0xffffu);
  H.u[3] = (y.w & 0xffff0000u) | (y.z >> 16);
  L.u[3] = (y.w << 16)         | (y.z & 0xffffu);
  ah = H.v; al = L.v;
}

// ---------------- small conversion kernels ----------------
__global__ void k_conv(const float* __restrict__ s, u16* __restrict__ d, int n){
  for (int i = blockIdx.x*256 + threadIdx.x; i < n; i += gridDim.x*256) d[i] = f2b(s[i]);
}
__global__ void k_split(const float* __restrict__ s, u16* __restrict__ dh, u16* __restrict__ dl, int n){
  for (int i = blockIdx.x*256 + threadIdx.x; i < n; i += gridDim.x*256){
    float v = s[i]; u16 hi = f2b(v); dh[i]=hi; dl[i]=f2b(v-b2f(hi));
  }
}
// pack h0 [32][1024] f32 into roll slot 0 rows [b][0..1024)
__global__ void k_pack0(const float* __restrict__ s, unsigned* __restrict__ d){
  int i = blockIdx.x*256 + threadIdx.x;
  if (i >= NB*NU) return;
  float v = s[i]; u16 hi = f2b(v); u16 lo = f2b(v-b2f(hi));
  d[(i>>10)*2048 + (i&1023)] = ((unsigned)hi<<16)|lo;
}
__global__ void k_gather(const int* __restrict__ toks, const float* __restrict__ emb, u16* __restrict__ x){
  int i = blockIdx.x*256 + threadIdx.x;
  if (i >= NB*NT*NE) return;
  int bt = i>>8, e = i&255;
  int b = bt/NT, t = bt - b*NT;
  int tok = toks[b*128 + t];                 // dec_in = output_batch[:, :-1]
  x[i] = f2b(emb[(size_t)tok*NE + e]);
}
// transpose f32 (R x C, row stride rs) -> bf16 hi/lo (C x dstStride) at dst[c*dstStride+dstOff+r]
__global__ void k_transpose(const float* __restrict__ src, int rs,
                            u16* __restrict__ dh, u16* __restrict__ dl,
                            int dstStride, int dstOff){
  __shared__ float tile[32][33];
  int tc = blockIdx.x*32, tr = blockIdx.y*32;
  int tx = threadIdx.x & 31, ty = threadIdx.x >> 5;
  #pragma unroll
  for (int rr=0; rr<4; ++rr){
    int r = ty + rr*8;
    tile[r][tx] = src[(size_t)(tr+r)*rs + tc + tx];
  }
  __syncthreads();
  #pragma unroll
  for (int rr=0; rr<4; ++rr){
    int cl = ty + rr*8;
    float v = tile[tx][cl];
    u16 hi = f2b(v);
    size_t o = (size_t)(tc+cl)*dstStride + dstOff + tr + tx;
    dh[o] = hi;
    if (dl) dl[o] = f2b(v - b2f(hi));
  }
}
// transpose+add f32 C[1024][4096] (+addS) -> bf16 hi/lo dst[4096][1024]
__global__ void k_fuseT(const float* __restrict__ C, const float* __restrict__ addS,
                        u16* __restrict__ dh, u16* __restrict__ dl){
  __shared__ float tile[32][33];
  int tc = blockIdx.x*32, tr = blockIdx.y*32;
  int tx = threadIdx.x & 31, ty = threadIdx.x >> 5;
  #pragma unroll
  for (int rr=0; rr<4; ++rr){
    int r = ty + rr*8;
    float v = C[(size_t)(tr+r)*4096 + tc + tx];
    if (addS) v += addS[(size_t)(tr+r)*4096 + tc + tx];
    tile[r][tx] = v;
  }
  __syncthreads();
  #pragma unroll
  for (int rr=0; rr<4; ++rr){
    int cl = ty + rr*8;
    float v = tile[tx][cl];
    u16 hi = f2b(v);
    size_t o = (size_t)(tc+cl)*1024 + tr + tx;
    dh[o] = hi; dl[o] = f2b(v - b2f(hi));
  }
}

// ---------------- generic 64x64-tile bf16 MFMA GEMM (single-term) ----------------
template<int OUTF, int BIAS>
__global__ __launch_bounds__(256) void k_gemm64(
    const u16* __restrict__ A, int lda,
    const u16* __restrict__ Bt, int ldb,
    float* __restrict__ Cf, u16* __restrict__ Cb, int ldc,
    const float* __restrict__ bias, int M, int K)
{
  __shared__ __align__(16) u16 As[64][40];
  __shared__ __align__(16) u16 Bs[64][40];
  int n0 = blockIdx.x*64, m0 = blockIdx.y*64;
  int tid = threadIdx.x, lane = tid & 63, w = tid>>6;
  int lr = tid>>2, lk = (tid&3)*8;
  f32x4 acc[4] = {};
  for (int kk=0; kk<K; kk+=32){
    uint4 av = make_uint4(0,0,0,0);
    int row = m0 + lr;
    if (row < M) av = *(const uint4*)(A + (size_t)row*lda + kk + lk);
    *(uint4*)(&As[lr][lk]) = av;
    uint4 bv = *(const uint4*)(Bt + (size_t)(n0+lr)*ldb + kk + lk);
    *(uint4*)(&Bs[lr][lk]) = bv;
    __syncthreads();
    bf16x8 af = *(const bf16x8*)(&As[w*16 + (lane&15)][(lane>>4)*8]);
    #pragma unroll
    for (int ni=0; ni<4; ++ni){
      bf16x8 bfr = *(const bf16x8*)(&Bs[ni*16 + (lane&15)][(lane>>4)*8]);
      acc[ni] = MFMA(af, bfr, acc[ni], 0,0,0);
    }
    __syncthreads();
  }
  #pragma unroll
  for (int ni=0; ni<4; ++ni){
    #pragma unroll
    for (int r=0; r<4; ++r){
      int row = m0 + w*16 + (lane>>4)*4 + r;
      int col = n0 + ni*16 + (lane&15);
      if (row < M){
        float v = acc[ni][r];
        if (BIAS) v += bias[col];
        if (OUTF==0) Cf[(size_t)row*ldc + col] = v;
        else         Cb[(size_t)row*ldc + col] = f2b(v);
      }
    }
  }
}

// ------- 128x128-tile, BK=32, 3-term split GEMM: (Ah+Al) x (Bh+Bl), N mult of 128 -------
template<int OUTF>
__global__ __launch_bounds__(256) void k_gemm128s(
    const u16* __restrict__ Ah, const u16* __restrict__ Al, int lda,
    const u16* __restrict__ Bh, const u16* __restrict__ Bl, int ldb,
    float* __restrict__ Cf, u16* __restrict__ Cb, int ldc, int M, int K)
{
  __shared__ __align__(16) u16 AsH[128][40], AsL[128][40], BsH[128][40], BsL[128][40];
  int n0 = blockIdx.x*128, m0 = blockIdx.y*128;
  int tid = threadIdx.x, lane = tid&63, wv = tid>>6;
  int lr = tid>>1, lk = (tid&1)*16;
  int wr = (wv>>1)*64, wc = (wv&1)*64;
  int l15 = lane&15, ko = (lane>>4)*8;
  f32x4 acc[4][4] = {};
  for (int kk=0; kk<K; kk+=32){
    uint4 z = make_uint4(0,0,0,0);
    uint4 ah0=z, ah1=z, al0=z, al1=z;
    int row = m0 + lr;
    if (row < M){
      ah0 = *(const uint4*)(Ah + (size_t)row*lda + kk + lk);
      ah1 = *(const uint4*)(Ah + (size_t)row*lda + kk + lk + 8);
      al0 = *(const uint4*)(Al + (size_t)row*lda + kk + lk);
      al1 = *(const uint4*)(Al + (size_t)row*lda + kk + lk + 8);
    }
    *(uint4*)&AsH[lr][lk]   = ah0;
    *(uint4*)&AsH[lr][lk+8] = ah1;
    *(uint4*)&AsL[lr][lk]   = al0;
    *(uint4*)&AsL[lr][lk+8] = al1;
    *(uint4*)&BsH[lr][lk]   = *(const uint4*)(Bh + (size_t)(n0+lr)*ldb + kk + lk);
    *(uint4*)&BsH[lr][lk+8] = *(const uint4*)(Bh + (size_t)(n0+lr)*ldb + kk + lk + 8);
    *(uint4*)&BsL[lr][lk]   = *(const uint4*)(Bl + (size_t)(n0+lr)*ldb + kk + lk);
    *(uint4*)&BsL[lr][lk+8] = *(const uint4*)(Bl + (size_t)(n0+lr)*ldb + kk + lk + 8);
    __syncthreads();
    bf16x8 afh[4], afl[4], bfh[4], bfl[4];
    #pragma unroll
    for (int i=0;i<4;++i){
      afh[i] = *(const bf16x8*)&AsH[wr+i*16+l15][ko];
      afl[i] = *(const bf16x8*)&AsL[wr+i*16+l15][ko];
      bfh[i] = *(const bf16x8*)&BsH[wc+i*16+l15][ko];
      bfl[i] = *(const bf16x8*)&BsL[wc+i*16+l15][ko];
    }
    #pragma unroll
    for (int mi=0;mi<4;++mi)
      #pragma unroll
      for (int ni=0;ni<4;++ni){
        acc[mi][ni] = MFMA(afh[mi], bfl[ni], acc[mi][ni], 0,0,0);
        acc[mi][ni] = MFMA(afl[mi], bfh[ni], acc[mi][ni], 0,0,0);
        acc[mi][ni] = MFMA(afh[mi], bfh[ni], acc[mi][ni], 0,0,0);
      }
    __syncthreads();
  }
  #pragma unroll
  for (int mi=0;mi<4;++mi){
    int rowb = m0 + wr + mi*16 + (lane>>4)*4;
    #pragma unroll
    for (int ni=0;ni<4;++ni){
      int col = n0 + wc + ni*16 + l15;
      #pragma unroll
      for (int r=0;r<4;++r){
        if (rowb + r < M){
          float v = acc[mi][ni][r];
          if (OUTF==0) Cf[(size_t)(rowb+r)*ldc + col] = v;
          else         Cb[(size_t)(rowb+r)*ldc + col] = f2b(v);
        }
      }
    }
  }
}

// ---------------- persistent recurrence kernel ----------------
struct PP {
  const u16 *WzhTH, *WzhTL;   // [4096][1024]
  const u16 *WzcTH, *WzcTL;   // [4096][1024]
  const u16 *Wr0TH, *Wr0TL;   // [4096][1024] (t=0 h-weight = W_r^T)
  const u16 *WqT;             // [1024][1024]
  const u16 *xW;              // rows b*NT+t, 4096 cols (bf16, bias folded)
  const u16 *keys;            // [4096][1024]
  const u16 *aB;              // [4096][1024]
  const float *v_att;         // [1024]
  const float *c0f;           // [32][1024] initial c (f32)
  unsigned *roll;             // [(NT+1)][32][2048] packed h|ctx — write-once rolling
  float *qroll;               // [NT][32][1024] — write-once, sentinel-init
  float *scroll;              // [NT][32][128] — write-once, sentinel-init
  u16 *hcH, *hcL;             // [4096][2048] hist [h | ctx] cached (read post-kernel)
  unsigned *flags;            // [256] per-block generation flags (no atomics!)
};

// zero-RMW barrier: post own flag (plain bypass store), poll flags wide w/ backoff.
DEVI void post(unsigned* myflag, unsigned gen){
  asm volatile("s_waitcnt vmcnt(0)" ::: "memory");   // per-wave: all stores committed
  __syncthreads();                                    // whole block drained
  if (threadIdx.x == 0) bstore(myflag, gen);
}
// wait until flags[0..nflags) >= gen. Wave 0 polls: lane i checks flags[4i..4i+3].
DEVI void waitall(const unsigned* flags, unsigned gen, int nflags){
  if (threadIdx.x < 64){
    int idx = (int)threadIdx.x * 4;
    bool active = idx < nflags;
    const unsigned* fp = flags + (active ? idx : 0);
    for (;;){
      uint4 f = bload4(fp);
      bool ok = !active || (f.x>=gen && f.y>=gen && f.z>=gen && f.w>=gen);
      if (__all(ok)) break;
      __builtin_amdgcn_s_sleep(4);
    }
  }
  __syncthreads();
}

__global__ __launch_bounds__(512,1) void k_persist(PP p){
  __shared__ float smem[4096];   // zs[8][32][16] | C2: alig[128]+psum[8][128]+scl[128]
  float (*zs)[32][16] = (float(*)[32][16])smem;
  int tid = threadIdx.x, lane = tid&63, wv = tid>>6, blk = blockIdx.x;
  int l15 = lane&15, ko = (lane>>4)*8;
  unsigned* flags = p.flags;
  unsigned* myflag = flags + blk;

  // ============ register preloads (cached RO, never invalidated — no fences) =========
  int u0 = blk*4;
  int wrow = (l15>>2)*1024 + u0 + (l15&3);
  size_t woff = (size_t)wrow*1024 + (wv&3)*256 + ko;
  const u16 *whG = (wv<4 ? p.Wr0TH : p.WzcTH) + woff;
  const u16 *wlG = (wv<4 ? p.Wr0TL : p.WzcTL) + woff;
  bf16x8 wH[8], wL[8];
  #pragma unroll
  for (int ki=0; ki<8; ++ki){
    wH[ki] = *(const bf16x8*)(whG + ki*32);
    wL[ki] = *(const bf16x8*)(wlG + ki*32);
  }
  bf16x8 wq[4];
  int nq0 = (blk&63)*16;
  if (blk < 64){
    const u16* qg = p.WqT + (size_t)(nq0+l15)*1024 + wv*128 + ko;
    #pragma unroll
    for (int ki=0; ki<4; ++ki) wq[ki] = *(const bf16x8*)(qg + ki*32);
  }
  // block-private LSTM cell state (register-resident)
  float creg = 0.f;
  if (tid < 128) creg = p.c0f[(tid>>2)*NU + u0 + (tid&3)];
  // phase-C mapping: co-locate a batch's 8 blocks on one XCD (XCD = blk%8)
  int m8 = blk>>3;
  int cb = (blk&7)*4 + (m8>>3);     // batch 0..31
  int c0 = (m8&7)*128;              // ctx col chunk
  int s0 = (m8&7)*16;               // score row chunk (C1)
  int cp = 2*(tid&63), sq8 = tid>>6;
  unsigned av[16];
  #pragma unroll
  for (int si=0; si<16; ++si)
    av[si] = *(const unsigned*)(p.aB + (size_t)(cb*128 + sq8*16 + si)*1024 + c0 + cp);
  // keys slice for C1 (rows s0+wv*2+{0,1}) — register-pinned
  u16x8 kr[2][2];
  #pragma unroll
  for (int si=0; si<2; ++si){
    const u16* kp = p.keys + (size_t)(cb*128 + s0 + wv*2 + si)*1024 + lane*16;
    kr[si][0] = *(const u16x8*)kp;
    kr[si][1] = *(const u16x8*)(kp + 8);
  }
  // v_att slice (loop-invariant)
  float vr[16];
  #pragma unroll
  for (int j=0; j<4; ++j)
    *(float4*)&vr[j*4] = *(const float4*)(p.v_att + lane*16 + j*4);

  for (int t=0; t<NT; ++t){
    unsigned g1 = 2u*t + 1u, g2 = 2u*t + 2u;
    unsigned* rollW = p.roll + (size_t)(t+1)*ROLLSTEP;   // this step's outputs
    // ---- phase A: z = xW + h@Wzh + ctx@Wzc -> gates -> h,c ----
    {
      float xw0=0.f, xw1=0.f, xw2=0.f, xw3=0.f;
      if (tid < 128){
        const u16* xw = p.xW + (size_t)((tid>>2)*NT + t)*4096 + u0 + (tid&3);
        xw0 = b2f(xw[0]); xw1 = b2f(xw[1024]); xw2 = b2f(xw[2048]); xw3 = b2f(xw[3072]);
      }
      // cached cold reads of [h|ctx] from roll[t] (write-once addresses => never stale)
      const unsigned* Apk = p.roll + (size_t)t*ROLLSTEP + (wv<4 ? 0 : 1024);
      int kb = (wv&3)*256;
      const unsigned* b0 = Apk + (size_t)l15*2048 + kb + ko;
      const unsigned* b1 = b0 + 16*2048;
      f32x4 acc0 = {}, acc1 = {};
      #pragma unroll
      for (int ki=0; ki<8; ++ki){
        uint4 x0 = *(const uint4*)(b0 + ki*32);
        uint4 y0 = *(const uint4*)(b0 + ki*32 + 4);
        uint4 x1 = *(const uint4*)(b1 + ki*32);
        uint4 y1 = *(const uint4*)(b1 + ki*32 + 4);
        bf16x8 a0h, a0l, a1h, a1l;
        unpack8(x0, y0, a0h, a0l);
        unpack8(x1, y1, a1h, a1l);
        acc0 = MFMA(a0h, wL[ki], acc0, 0,0,0);
        acc0 = MFMA(a0l, wH[ki], acc0, 0,0,0);
        acc0 = MFMA(a0h, wH[ki], acc0, 0,0,0);
        acc1 = MFMA(a1h, wL[ki], acc1, 0,0,0);
        acc1 = MFMA(a1l, wH[ki], acc1, 0,0,0);
        acc1 = MFMA(a1h, wH[ki], acc1, 0,0,0);
      }
      if (t == 0 && wv < 4){   // swap Wr0 -> steady-state Wzh (hidden under B/C)
        const u16* nh = p.WzhTH + woff;
        const u16* nl = p.WzhTL + woff;
        #pragma unroll
        for (int ki=0; ki<8; ++ki){
          wH[ki] = *(const bf16x8*)(nh + ki*32);
          wL[ki] = *(const bf16x8*)(nl + ki*32);
        }
      }
      #pragma unroll
      for (int r=0; r<4; ++r){
        zs[wv][(lane>>4)*4 + r][l15]      = acc0[r];
        zs[wv][16 + (lane>>4)*4 + r][l15] = acc1[r];
      }
      __syncthreads();
      if (tid < 128){
        int b = tid>>2, du = tid&3;
        float zg[4];
        #pragma unroll
        for (int g=0; g<4; ++g){
          float v = 0.f;
          #pragma unroll
          for (int w=0; w<8; ++w) v += zs[w][b][g*4+du];
          zg[g] = v;
        }
        zg[0] += xw0; zg[1] += xw1; zg[2] += xw2; zg[3] += xw3;
        float i_ = sigm(zg[0]), f_ = sigm(zg[1]), g_ = tanh_(zg[2]), o_ = sigm(zg[3]);
        float cn = f_*creg + i_*g_;
        creg = cn;
        float h = o_*tanh_(cn);
        u16 hi = f2b(h), lo = f2b(h - b2f(hi));
        bstore(&rollW[b*2048 + u0 + du], ((unsigned)hi<<16)|lo);  // bypass, write-once
        size_t ho = (size_t)(b*NT + t)*2048 + u0 + du;
        p.hcH[ho] = hi; p.hcL[ho] = lo;                           // history, cached
      }
    }
    post(myflag, g1);
    // ---- phase B: q = h@W_q (blocks 0..63; others fall through to C1's q-poll) ----
    if (blk < 64){
      waitall(flags, g1, 256);
      const unsigned* b0 = rollW + (size_t)l15*2048 + wv*128 + ko;
      const unsigned* b1 = b0 + 16*2048;
      f32x4 acc0 = {}, acc1 = {};
      #pragma unroll
      for (int ki=0; ki<4; ++ki){
        uint4 x0 = *(const uint4*)(b0 + ki*32);
        uint4 y0 = *(const uint4*)(b0 + ki*32 + 4);
        uint4 x1 = *(const uint4*)(b1 + ki*32);
        uint4 y1 = *(const uint4*)(b1 + ki*32 + 4);
        bf16x8 a0h, a0l, a1h, a1l;
        unpack8(x0, y0, a0h, a0l);
        unpack8(x1, y1, a1h, a1l);
        acc0 = MFMA(a0l, wq[ki], acc0, 0,0,0);
        acc0 = MFMA(a0h, wq[ki], acc0, 0,0,0);
        acc1 = MFMA(a1l, wq[ki], acc1, 0,0,0);
        acc1 = MFMA(a1h, wq[ki], acc1, 0,0,0);
      }
      #pragma unroll
      for (int r=0; r<4; ++r){
        zs[wv][(lane>>4)*4 + r][l15]      = acc0[r];
        zs[wv][16 + (lane>>4)*4 + r][l15] = acc1[r];
      }
      __syncthreads();
      {
        int b = tid>>4, c = tid&15;
        float v = 0.f;
        #pragma unroll
        for (int w=0; w<8; ++w) v += zs[w][b][c];
        bstoref(&p.qroll[(size_t)t*32768 + b*NU + nq0 + c], v);   // bypass, write-once
      }
    }
    // ---- dataflow sync: wave 0 polls q[cb][*] for sentinel-free ----
    {
      if (tid < 64){
        const unsigned* qp = (const unsigned*)(p.qroll + (size_t)t*32768 + cb*NU) + tid*16;
        for (;;){
          uint4 a = bload4(qp), b = bload4(qp+4), c = bload4(qp+8), d = bload4(qp+12);
          bool ok = a.x!=SENT && a.y!=SENT && a.z!=SENT && a.w!=SENT
                 && b.x!=SENT && b.y!=SENT && b.z!=SENT && b.w!=SENT
                 && c.x!=SENT && c.y!=SENT && c.z!=SENT && c.w!=SENT
                 && d.x!=SENT && d.y!=SENT && d.z!=SENT && d.w!=SENT;
          if (__all(ok)) break;
          __builtin_amdgcn_s_sleep(4);
        }
      }
      __syncthreads();
    }
    // ---- phase C1: own 16 score rows (keys in registers; q cached cold, now valid) ----
    {
      const float* qp = p.qroll + (size_t)t*32768 + cb*NU + lane*16;
      float qr[16];
      #pragma unroll
      for (int j=0; j<4; ++j)
        *(float4*)&qr[j*4] = *(const float4*)(qp + j*4);
      #pragma unroll
      for (int si=0; si<2; ++si){
        float pv = 0.f;
        #pragma unroll
        for (int j=0; j<8; ++j) pv += vr[j]   * tanh_(b2f(kr[si][0][j]) + qr[j]);
        #pragma unroll
        for (int j=0; j<8; ++j) pv += vr[8+j] * tanh_(b2f(kr[si][1][j]) + qr[8+j]);
        #pragma unroll
        for (int off=32; off; off>>=1) pv += __shfl_xor(pv, off);
        if (lane==0) bstoref(&p.scroll[(size_t)t*4096 + cb*128 + s0 + wv*2 + si], pv);
      }
    }
    // ---- phase C2: dataflow-poll scores, softmax + ctx chunk (aB in registers) ----
    {
      float* alig = smem;          // [128]
      float* psum = smem + 128;    // [8][128]
      float* scl  = smem + 1280;   // [128]
      if (tid < 64){
        bool act = tid < 32;
        const unsigned* sp = (const unsigned*)(p.scroll + (size_t)t*4096 + cb*128)
                             + (act ? tid*4 : 0);
        for (;;){
          uint4 sv = bload4(sp);
          bool ok = !act || (sv.x!=SENT && sv.y!=SENT && sv.z!=SENT && sv.w!=SENT);
          if (__all(ok)){ if (act) *(uint4*)&scl[tid*4] = sv; break; }
          __builtin_amdgcn_s_sleep(2);
        }
      }
      __syncthreads();
      if (tid < 64){
        float sA = scl[tid], sB = scl[64 + tid];
        float m = fmaxf(sA, sB);
        #pragma unroll
        for (int off=32; off; off>>=1) m = fmaxf(m, __shfl_xor(m, off));
        float e0 = __expf(sA-m), e1 = __expf(sB-m);
        float sum = e0+e1;
        #pragma unroll
        for (int off=32; off; off>>=1) sum += __shfl_xor(sum, off);
        float inv = frcp(sum);
        alig[tid] = e0*inv; alig[tid+64] = e1*inv;
      }
      __syncthreads();
      {
        float ax = 0.f, ay = 0.f;
        #pragma unroll
        for (int si=0; si<16; ++si){
          unsigned kv = av[si];
          float al = alig[sq8*16 + si];
          ax += al*b2f((u16)(kv & 0xffffu));
          ay += al*b2f((u16)(kv >> 16));
        }
        psum[sq8*128 + cp]   = ax;
        psum[sq8*128 + cp+1] = ay;
      }
      __syncthreads();
      if (tid < 128){
        float v = 0.f;
        #pragma unroll
        for (int s8=0; s8<8; ++s8) v += psum[s8*128 + tid];
        int col = c0 + tid;
        u16 hi = f2b(v), lo = f2b(v - b2f(hi));
        bstore(&rollW[cb*2048 + 1024 + col], ((unsigned)hi<<16)|lo);  // bypass, write-once
        size_t ho = (size_t)(cb*NT + t)*2048 + 1024 + col;
        p.hcH[ho] = hi; p.hcL[ho] = lo;                               // history, cached
      }
    }
    post(myflag, g2);
    waitall(flags, g2, 256);
  }
}

// ---------------- logits: 128x128-tile, BK=64, double-buffered reg-staged ----------------
#define LDSK 72
__global__ __launch_bounds__(256) void k_logits(
    const u16* __restrict__ A,   // [4096][1024]
    const u16* __restrict__ Bt,  // [32000][1024]
    const float* __restrict__ bias,
    float* __restrict__ C)
{
  __shared__ __align__(16) u16 As[128*LDSK];
  __shared__ __align__(16) u16 Bs[128*LDSK];
  int tid = threadIdx.x, lane = tid&63, wv = tid>>6;
  int m0 = blockIdx.y*128, n0 = blockIdx.x*128;
  int wr = (wv>>1)*64, wc = (wv&1)*64;
  int l15 = lane&15, ko = (lane>>4)*8;
  int srow = tid>>3, sc8 = (tid&7)*8;
  f32x4 acc[4][4] = {};
  uint4 a0[4], b0[4], a1[4], b1[4];

  #define LOADG(ar, br, kk) { \
    _Pragma("unroll") \
    for (int i=0;i<4;++i){ \
      ar[i] = *(const uint4*)(A  + (size_t)(m0+srow+i*32)*1024 + (kk) + sc8); \
      br[i] = *(const uint4*)(Bt + (size_t)(n0+srow+i*32)*1024 + (kk) + sc8); \
    } }
  #define STORES(ar, br) { \
    _Pragma("unroll") \
    for (int i=0;i<4;++i){ \
      *(uint4*)(&As[(srow+i*32)*LDSK + sc8]) = ar[i]; \
      *(uint4*)(&Bs[(srow+i*32)*LDSK + sc8]) = br[i]; \
    } }
  #define COMPUTE() { \
    _Pragma("unroll") \
    for (int ks=0; ks<2; ++ks){ \
      bf16x8 af[4], bf[4]; \
      _Pragma("unroll") \
      for (int i=0;i<4;++i){ \
        af[i] = *(const bf16x8*)(&As[(wr+i*16+l15)*LDSK + ks*32 + ko]); \
        bf[i] = *(const bf16x8*)(&Bs[(wc+i*16+l15)*LDSK + ks*32 + ko]); \
      } \
      _Pragma("unroll") \
      for (int mi=0;mi<4;++mi) \
        _Pragma("unroll") \
        for (int ni=0;ni<4;++ni) \
          acc[mi][ni] = MFMA(af[mi], bf[ni], acc[mi][ni], 0,0,0); \
    } }

  LOADG(a0, b0, 0);
  for (int kk=0; kk<1024; kk+=128){
    __syncthreads();
    STORES(a0, b0);
    if (kk+64 < 1024) LOADG(a1, b1, kk+64);
    __syncthreads();
    COMPUTE();
    __syncthreads();
    STORES(a1, b1);
    if (kk+128 < 1024) LOADG(a0, b0, kk+128);
    __syncthreads();
    COMPUTE();
  }
  #pragma unroll
  for (int mi=0; mi<4; ++mi){
    int row = m0 + wr + mi*16 + (lane>>4)*4;
    #pragma unroll
    for (int ni=0; ni<4; ++ni){
      int col = n0 + wc + ni*16 + l15;
      float bval = bias[col];
      #pragma unroll
      for (int r=0; r<4; ++r){
        if (row + r < NB*NT)
          C[(size_t)(row+r)*NV + col] = acc[mi][ni][r] + bval;
      }
    }
  }
  #undef LOADG
  #undef STORES
  #undef COMPUTE
}

// ---------------- host ----------------
extern "C" void kernel_launch(void* const* d_in, const int* in_sizes, int n_in,
                              void* d_out, int out_size, void* d_ws, size_t ws_size,
                              hipStream_t stream)
{
  (void)in_sizes; (void)n_in; (void)out_size; (void)ws_size;
  const int*   toks  = (const int*)  d_in[0];
  const float* a_in  = (const float*)d_in[1];
  const float* a_tx  = (const float*)d_in[2];
  const float* c_tx  = (const float*)d_in[3];
  const float* emb   = (const float*)d_in[4];
  const float* W_k   = (const float*)d_in[5];
  const float* W_r   = (const float*)d_in[6];
  const float* bvec  = (const float*)d_in[7];
  const float* W_m   = (const float*)d_in[8];
  const float* W_q   = (const float*)d_in[9];
  const float* v_att = (const float*)d_in[10];
  const float* W_a   = (const float*)d_in[11];
  const float* W_o   = (const float*)d_in[12];
  const float* b_o   = (const float*)d_in[13];
  float* out = (float*)d_out;

  char* p = (char*)d_ws;
  auto alloc = [&](size_t bytes)->char*{ char* r = p; p += (bytes + 255) & ~(size_t)255; return r; };

  u16* WzhTH = (u16*)alloc((size_t)4096*1024*2);
  u16* WzhTL = (u16*)alloc((size_t)4096*1024*2);
  u16* WzcTH = (u16*)alloc((size_t)4096*1024*2);
  u16* WzcTL = (u16*)alloc((size_t)4096*1024*2);
  u16* Wr0TH = (u16*)alloc((size_t)4096*1024*2);   // reused as outsH after persist
  u16* Wr0TL = (u16*)alloc((size_t)4096*1024*2);
  u16* WqT   = (u16*)alloc((size_t)1024*1024*2);
  u16* WaTH  = (u16*)alloc((size_t)1024*2048*2);
  u16* WaTL  = (u16*)alloc((size_t)1024*2048*2);
  u16* WmT   = (u16*)alloc((size_t)1024*1024*2);
  u16* WoT   = (u16*)alloc((size_t)NV*1024*2);
  u16* WkxT  = (u16*)alloc((size_t)4096*256*2);
  u16* xB    = (u16*)alloc((size_t)4096*256*2);
  u16* xWb   = (u16*)alloc((size_t)4096*4096*2);
  u16* aB    = (u16*)alloc((size_t)4096*1024*2);
  u16* keysB = (u16*)alloc((size_t)4096*1024*2);
  // union region: prep { WkaT h/l, WaRow h/l, tmpF } -> persist { hcH, hcL }
  char* uni  = alloc((size_t)44*1024*1024);
  u16* WkaTH  = (u16*)uni;
  u16* WkaTL  = WkaTH + (size_t)4096*1024;
  u16* WaRowH = WkaTL + (size_t)4096*1024;
  u16* WaRowL = WaRowH + (size_t)2048*1024;
  float* tmpF = (float*)(WaRowL + (size_t)2048*1024);
  u16* hcH = (u16*)uni;
  u16* hcL = hcH + (size_t)4096*2048;

  unsigned* roll   = (unsigned*)alloc((size_t)(NT+1)*ROLLSTEP*4);   // 33.6 MB
  float*    qroll  = (float*)alloc((size_t)NT*NB*NU*4);             // 16.6 MB
  float*    scroll = (float*)alloc((size_t)NT*NB*128*4);            // 2.1 MB
  unsigned* flags  = (unsigned*)alloc(4096);
  u16* outsH = Wr0TH;   // overlap (Wr0T dead after persist prologue)

  // ---- init ----
  (void)hipMemsetAsync(flags, 0, 4096, stream);
  (void)hipMemsetAsync(roll, 0, (size_t)ROLLSTEP*4, stream);   // slot 0 (ctx0 = 0)
  (void)hipMemsetAsync(qroll, 0xFF, (size_t)NT*NB*NU*4, stream);     // sentinel
  (void)hipMemsetAsync(scroll, 0xFF, (size_t)NT*NB*128*4, stream);   // sentinel
  k_pack0<<<128,256,0,stream>>>(a_tx, roll);
  k_split<<<2048,256,0,stream>>>(W_a, WaRowH, WaRowL, 2048*1024);
  k_gather<<<(NB*NT*NE)/256,256,0,stream>>>(toks, emb, xB);
  k_conv<<<2048,256,0,stream>>>(a_in, aB, NB*128*NU);

  // ---- weight transposes ----
  k_transpose<<<dim3(128,32),256,0,stream>>>(W_k + (size_t)256*4096, 4096, WkaTH, WkaTL, 1024, 0);
  k_transpose<<<dim3(128,32),256,0,stream>>>(W_r, 4096, Wr0TH, Wr0TL, 1024, 0);
  k_transpose<<<dim3(32,32),256,0,stream>>>(W_q, 1024, WqT, nullptr, 1024, 0);
  k_transpose<<<dim3(32,64),256,0,stream>>>(W_a, 1024, WaTH, WaTL, 2048, 0);
  k_transpose<<<dim3(32,32),256,0,stream>>>(W_m, 1024, WmT, nullptr, 1024, 0);
  k_transpose<<<dim3(1000,32),256,0,stream>>>(W_o, NV, WoT, nullptr, 1024, 0);
  k_transpose<<<dim3(128,8),256,0,stream>>>(W_k, 4096, WkxT, nullptr, 256, 0);

  // ---- precompute GEMMs ----
  // keys = a @ W_m
  k_gemm64<1,0><<<dim3(16,64),256,0,stream>>>(aB, 1024, WmT, 1024, nullptr, keysB, 1024, nullptr, 4096, 1024);
  // xW = x @ W_k[0:256] + b
  k_gemm64<1,1><<<dim3(64,64),256,0,stream>>>(xB, 256, WkxT, 256, nullptr, xWb, 4096, bvec, NB*NT, 256);
  // Wzh = W_r + W_a[0:1024] @ Wk_attn  (3-term split, f32, then transpose+split)
  k_gemm128s<0><<<dim3(32,8),256,0,stream>>>(WaRowH, WaRowL, 1024, WkaTH, WkaTL, 1024,
                                             tmpF, nullptr, 4096, 1024, 1024);
  k_fuseT<<<dim3(128,32),256,0,stream>>>(tmpF, W_r, WzhTH, WzhTL);
  // Wzc = W_a[1024:2048] @ Wk_attn
  k_gemm128s<0><<<dim3(32,8),256,0,stream>>>(WaRowH + (size_t)1024*1024, WaRowL + (size_t)1024*1024, 1024,
                                             WkaTH, WkaTL, 1024, tmpF, nullptr, 4096, 1024, 1024);
  k_fuseT<<<dim3(128,32),256,0,stream>>>(tmpF, nullptr, WzcTH, WzcTL);

  // ---- persistent recurrence ----
  PP pp;
  pp.WzhTH=WzhTH; pp.WzhTL=WzhTL; pp.WzcTH=WzcTH; pp.WzcTL=WzcTL;
  pp.Wr0TH=Wr0TH; pp.Wr0TL=Wr0TL; pp.WqT=WqT; pp.xW=xWb;
  pp.keys=keysB; pp.aB=aB; pp.v_att=v_att; pp.c0f=c_tx;
  pp.roll=roll; pp.qroll=qroll; pp.scroll=scroll;
  pp.hcH=hcH; pp.hcL=hcL; pp.flags=flags;
  k_persist<<<NBLK,512,0,stream>>>(pp);

  // ---- outs = [h|ctx] @ W_a  (3-term split, bf16 out, 128-tile) ----
  k_gemm128s<1><<<dim3(8,32),256,0,stream>>>(hcH, hcL, 2048, WaTH, WaTL, 2048,
                                             nullptr, outsH, 1024, NB*NT, 2048);

  // ---- logits = outs @ W_o + b_o ----
  k_logits<<<dim3(NV/128, 32),256,0,stream>>>(outsH, WoT, b_o, out);
}

// Round 15
// 3848.647 us; speedup vs baseline: 1.5738x; 1.2976x over previous
//
#include <hip/hip_runtime.h>
#include <cstdint>

#define DEVI __device__ __forceinline__

typedef unsigned short u16;
typedef __bf16 bf16x8 __attribute__((ext_vector_type(8)));
typedef u16 u16x8 __attribute__((ext_vector_type(8)));
typedef float f32x4 __attribute__((ext_vector_type(4)));

// B=32, T=128 (127 decode steps), V=32000, E=256, U=AU=M=1024, S=128
#define NB 32
#define NT 127
#define NV 32000
#define NE 256
#define NU 1024
#define NBLK 256
#define ROLLSTEP 65536   // 32*2048 u32 per step slot
#define SENT 0xFFFFFFFFu

typedef const __attribute__((address_space(1))) unsigned GU;
typedef __attribute__((address_space(3))) unsigned LU;

DEVI float b2f(u16 h){ union{unsigned u; float f;} v; v.u = ((unsigned)h)<<16; return v.f; }
DEVI u16 f2b(float f){ union{float f; unsigned u;} v; v.f=f; unsigned u=v.u;
                       return (u16)((u + 0x7fffu + ((u>>16)&1u))>>16); }
DEVI float frcp(float x){ return __builtin_amdgcn_rcpf(x); }
DEVI float sigm(float x){ return frcp(1.f+__expf(-x)); }
DEVI float tanh_(float x){ return 1.f - 2.f*frcp(1.f+__expf(2.f*x)); }
#define MFMA __builtin_amdgcn_mfma_f32_16x16x32_bf16

// ---- coherent-bypass stores (sc0 sc1) and poll loads ----
DEVI void bstore(unsigned* p, unsigned v){
  asm volatile("global_store_dword %0, %1, off sc0 sc1" :: "v"(p), "v"(v) : "memory");
}
DEVI void bstoref(float* p, float v){
  asm volatile("global_store_dword %0, %1, off sc0 sc1" :: "v"(p), "v"(v) : "memory");
}
DEVI uint4 bload4(const unsigned* p){
  uint4 f;
  asm volatile("global_load_dwordx4 %0, %1, off sc0 sc1\n\ts_waitcnt vmcnt(0)"
               : "=v"(f) : "v"(p) : "memory");
  return f;
}
// unpack 8 packed words (hi<<16|lo) -> hi/lo bf16x8
DEVI void unpack8(uint4 x, uint4 y, bf16x8& ah, bf16x8& al){
  union { unsigned u[4]; bf16x8 v; } H, L;
  H.u[0] = (x.y & 0xffff0000u) | (x.x >> 16);
  L.u[0] = (x.y << 16)         | (x.x & 0xffffu);
  H.u[1] = (x.w & 0xffff0000u) | (x.z >> 16);
  L.u[1] = (x.w << 16)         | (x.z & 0xffffu);
  H.u[2] = (y.y & 0xffff0000u) | (y.x >> 16);
  L.u[2] = (y.y << 16)         | (y.x & 0xffffu);
  H.u[3] = (y.w & 0xffff0000u) | (y.z >> 16);
  L.u[3] = (y.w << 16)         | (y.z & 0xffffu);
  ah = H.v; al = L.v;
}

// ---------------- small conversion kernels ----------------
__global__ void k_conv(const float* __restrict__ s, u16* __restrict__ d, int n){
  for (int i = blockIdx.x*256 + threadIdx.x; i < n; i += gridDim.x*256) d[i] = f2b(s[i]);
}
__global__ void k_split(const float* __restrict__ s, u16* __restrict__ dh, u16* __restrict__ dl, int n){
  for (int i = blockIdx.x*256 + threadIdx.x; i < n; i += gridDim.x*256){
    float v = s[i]; u16 hi = f2b(v); dh[i]=hi; dl[i]=f2b(v-b2f(hi));
  }
}
// pack h0 [32][1024] f32 into roll slot 0 rows [b][0..1024)
__global__ void k_pack0(const float* __restrict__ s, unsigned* __restrict__ d){
  int i = blockIdx.x*256 + threadIdx.x;
  if (i >= NB*NU) return;
  float v = s[i]; u16 hi = f2b(v); u16 lo = f2b(v-b2f(hi));
  d[(i>>10)*2048 + (i&1023)] = ((unsigned)hi<<16)|lo;
}
__global__ void k_gather(const int* __restrict__ toks, const float* __restrict__ emb, u16* __restrict__ x){
  int i = blockIdx.x*256 + threadIdx.x;
  if (i >= NB*NT*NE) return;
  int bt = i>>8, e = i&255;
  int b = bt/NT, t = bt - b*NT;
  int tok = toks[b*128 + t];                 // dec_in = output_batch[:, :-1]
  x[i] = f2b(emb[(size_t)tok*NE + e]);
}
// transpose f32 (R x C, row stride rs) -> bf16 hi/lo (C x dstStride) at dst[c*dstStride+dstOff+r]
__global__ void k_transpose(const float* __restrict__ src, int rs,
                            u16* __restrict__ dh, u16* __restrict__ dl,
                            int dstStride, int dstOff){
  __shared__ float tile[32][33];
  int tc = blockIdx.x*32, tr = blockIdx.y*32;
  int tx = threadIdx.x & 31, ty = threadIdx.x >> 5;
  #pragma unroll
  for (int rr=0; rr<4; ++rr){
    int r = ty + rr*8;
    tile[r][tx] = src[(size_t)(tr+r)*rs + tc + tx];
  }
  __syncthreads();
  #pragma unroll
  for (int rr=0; rr<4; ++rr){
    int cl = ty + rr*8;
    float v = tile[tx][cl];
    u16 hi = f2b(v);
    size_t o = (size_t)(tc+cl)*dstStride + dstOff + tr + tx;
    dh[o] = hi;
    if (dl) dl[o] = f2b(v - b2f(hi));
  }
}
// transpose+add f32 C[1024][4096] (+addS) -> bf16 hi/lo dst[4096][1024]
__global__ void k_fuseT(const float* __restrict__ C, const float* __restrict__ addS,
                        u16* __restrict__ dh, u16* __restrict__ dl){
  __shared__ float tile[32][33];
  int tc = blockIdx.x*32, tr = blockIdx.y*32;
  int tx = threadIdx.x & 31, ty = threadIdx.x >> 5;
  #pragma unroll
  for (int rr=0; rr<4; ++rr){
    int r = ty + rr*8;
    float v = C[(size_t)(tr+r)*4096 + tc + tx];
    if (addS) v += addS[(size_t)(tr+r)*4096 + tc + tx];
    tile[r][tx] = v;
  }
  __syncthreads();
  #pragma unroll
  for (int rr=0; rr<4; ++rr){
    int cl = ty + rr*8;
    float v = tile[tx][cl];
    u16 hi = f2b(v);
    size_t o = (size_t)(tc+cl)*1024 + tr + tx;
    dh[o] = hi; dl[o] = f2b(v - b2f(hi));
  }
}

// ---------------- generic 64x64-tile bf16 MFMA GEMM (single-term) ----------------
template<int OUTF, int BIAS>
__global__ __launch_bounds__(256) void k_gemm64(
    const u16* __restrict__ A, int lda,
    const u16* __restrict__ Bt, int ldb,
    float* __restrict__ Cf, u16* __restrict__ Cb, int ldc,
    const float* __restrict__ bias, int M, int K)
{
  __shared__ __align__(16) u16 As[64][40];
  __shared__ __align__(16) u16 Bs[64][40];
  int n0 = blockIdx.x*64, m0 = blockIdx.y*64;
  int tid = threadIdx.x, lane = tid & 63, w = tid>>6;
  int lr = tid>>2, lk = (tid&3)*8;
  f32x4 acc[4] = {};
  for (int kk=0; kk<K; kk+=32){
    uint4 av = make_uint4(0,0,0,0);
    int row = m0 + lr;
    if (row < M) av = *(const uint4*)(A + (size_t)row*lda + kk + lk);
    *(uint4*)(&As[lr][lk]) = av;
    uint4 bv = *(const uint4*)(Bt + (size_t)(n0+lr)*ldb + kk + lk);
    *(uint4*)(&Bs[lr][lk]) = bv;
    __syncthreads();
    bf16x8 af = *(const bf16x8*)(&As[w*16 + (lane&15)][(lane>>4)*8]);
    #pragma unroll
    for (int ni=0; ni<4; ++ni){
      bf16x8 bfr = *(const bf16x8*)(&Bs[ni*16 + (lane&15)][(lane>>4)*8]);
      acc[ni] = MFMA(af, bfr, acc[ni], 0,0,0);
    }
    __syncthreads();
  }
  #pragma unroll
  for (int ni=0; ni<4; ++ni){
    #pragma unroll
    for (int r=0; r<4; ++r){
      int row = m0 + w*16 + (lane>>4)*4 + r;
      int col = n0 + ni*16 + (lane&15);
      if (row < M){
        float v = acc[ni][r];
        if (BIAS) v += bias[col];
        if (OUTF==0) Cf[(size_t)row*ldc + col] = v;
        else         Cb[(size_t)row*ldc + col] = f2b(v);
      }
    }
  }
}

// ------- 128x128-tile, BK=32, 3-term split GEMM: (Ah+Al) x (Bh+Bl), N mult of 128 -------
template<int OUTF>
__global__ __launch_bounds__(256) void k_gemm128s(
    const u16* __restrict__ Ah, const u16* __restrict__ Al, int lda,
    const u16* __restrict__ Bh, const u16* __restrict__ Bl, int ldb,
    float* __restrict__ Cf, u16* __restrict__ Cb, int ldc, int M, int K)
{
  __shared__ __align__(16) u16 AsH[128][40], AsL[128][40], BsH[128][40], BsL[128][40];
  int n0 = blockIdx.x*128, m0 = blockIdx.y*128;
  int tid = threadIdx.x, lane = tid&63, wv = tid>>6;
  int lr = tid>>1, lk = (tid&1)*16;
  int wr = (wv>>1)*64, wc = (wv&1)*64;
  int l15 = lane&15, ko = (lane>>4)*8;
  f32x4 acc[4][4] = {};
  for (int kk=0; kk<K; kk+=32){
    uint4 z = make_uint4(0,0,0,0);
    uint4 ah0=z, ah1=z, al0=z, al1=z;
    int row = m0 + lr;
    if (row < M){
      ah0 = *(const uint4*)(Ah + (size_t)row*lda + kk + lk);
      ah1 = *(const uint4*)(Ah + (size_t)row*lda + kk + lk + 8);
      al0 = *(const uint4*)(Al + (size_t)row*lda + kk + lk);
      al1 = *(const uint4*)(Al + (size_t)row*lda + kk + lk + 8);
    }
    *(uint4*)&AsH[lr][lk]   = ah0;
    *(uint4*)&AsH[lr][lk+8] = ah1;
    *(uint4*)&AsL[lr][lk]   = al0;
    *(uint4*)&AsL[lr][lk+8] = al1;
    *(uint4*)&BsH[lr][lk]   = *(const uint4*)(Bh + (size_t)(n0+lr)*ldb + kk + lk);
    *(uint4*)&BsH[lr][lk+8] = *(const uint4*)(Bh + (size_t)(n0+lr)*ldb + kk + lk + 8);
    *(uint4*)&BsL[lr][lk]   = *(const uint4*)(Bl + (size_t)(n0+lr)*ldb + kk + lk);
    *(uint4*)&BsL[lr][lk+8] = *(const uint4*)(Bl + (size_t)(n0+lr)*ldb + kk + lk + 8);
    __syncthreads();
    bf16x8 afh[4], afl[4], bfh[4], bfl[4];
    #pragma unroll
    for (int i=0;i<4;++i){
      afh[i] = *(const bf16x8*)&AsH[wr+i*16+l15][ko];
      afl[i] = *(const bf16x8*)&AsL[wr+i*16+l15][ko];
      bfh[i] = *(const bf16x8*)&BsH[wc+i*16+l15][ko];
      bfl[i] = *(const bf16x8*)&BsL[wc+i*16+l15][ko];
    }
    #pragma unroll
    for (int mi=0;mi<4;++mi)
      #pragma unroll
      for (int ni=0;ni<4;++ni){
        acc[mi][ni] = MFMA(afh[mi], bfl[ni], acc[mi][ni], 0,0,0);
        acc[mi][ni] = MFMA(afl[mi], bfh[ni], acc[mi][ni], 0,0,0);
        acc[mi][ni] = MFMA(afh[mi], bfh[ni], acc[mi][ni], 0,0,0);
      }
    __syncthreads();
  }
  #pragma unroll
  for (int mi=0;mi<4;++mi){
    int rowb = m0 + wr + mi*16 + (lane>>4)*4;
    #pragma unroll
    for (int ni=0;ni<4;++ni){
      int col = n0 + wc + ni*16 + l15;
      #pragma unroll
      for (int r=0;r<4;++r){
        if (rowb + r < M){
          float v = acc[mi][ni][r];
          if (OUTF==0) Cf[(size_t)(rowb+r)*ldc + col] = v;
          else         Cb[(size_t)(rowb+r)*ldc + col] = f2b(v);
        }
      }
    }
  }
}

// ---------------- persistent recurrence kernel ----------------
struct PP {
  const u16 *WzhTH, *WzhTL;   // [4096][1024]
  const u16 *WzcTH, *WzcTL;   // [4096][1024]
  const u16 *Wr0TH, *Wr0TL;   // [4096][1024] (t=0 h-weight = W_r^T)
  const u16 *WqT;             // [1024][1024]
  const u16 *xW;              // rows b*NT+t, 4096 cols (bf16, bias folded)
  const u16 *keys;            // [4096][1024]
  const u16 *aB;              // [4096][1024]
  const float *v_att;         // [1024]
  const float *c0f;           // [32][1024] initial c (f32)
  unsigned *roll;             // [(NT+1)][32][2048] packed h|ctx — write-once rolling
  float *qroll;               // [NT][32][1024] — write-once, sentinel-init
  float *scroll;              // [NT][32][128] — write-once, sentinel-init
  u16 *hcH, *hcL;             // [4096][2048] hist [h | ctx] cached (read post-kernel)
  unsigned *flags;            // [256] per-block generation flags (no atomics!)
};

// zero-RMW barrier: post own flag (plain bypass store), poll flags wide w/ backoff.
DEVI void post(unsigned* myflag, unsigned gen){
  asm volatile("s_waitcnt vmcnt(0)" ::: "memory");   // per-wave: all stores committed
  __syncthreads();                                    // whole block drained
  if (threadIdx.x == 0) bstore(myflag, gen);
}
// wait until flags[0..nflags) >= gen. Wave 0 polls: lane i checks flags[4i..4i+3].
DEVI void waitall(const unsigned* flags, unsigned gen, int nflags){
  if (threadIdx.x < 64){
    int idx = (int)threadIdx.x * 4;
    bool active = idx < nflags;
    const unsigned* fp = flags + (active ? idx : 0);
    for (;;){
      uint4 f = bload4(fp);
      bool ok = !active || (f.x>=gen && f.y>=gen && f.z>=gen && f.w>=gen);
      if (__all(ok)) break;
      __builtin_amdgcn_s_sleep(4);
    }
  }
  __syncthreads();
}

__global__ __launch_bounds__(512,1) void k_persist(PP p){
  __shared__ float smem[4096];   // zs[8][32][16] | C2: alig[128]+psum[8][128]+scl[128]
  float (*zs)[32][16] = (float(*)[32][16])smem;
  int tid = threadIdx.x, lane = tid&63, wv = tid>>6, blk = blockIdx.x;
  int l15 = lane&15, ko = (lane>>4)*8;
  unsigned* flags = p.flags;
  unsigned* myflag = flags + blk;

  // ============ register preloads (cached RO, never invalidated — no fences) =========
  int u0 = blk*4;
  int wrow = (l15>>2)*1024 + u0 + (l15&3);
  size_t woff = (size_t)wrow*1024 + (wv&3)*256 + ko;
  const u16 *whG = (wv<4 ? p.Wr0TH : p.WzcTH) + woff;
  const u16 *wlG = (wv<4 ? p.Wr0TL : p.WzcTL) + woff;
  bf16x8 wH[8], wL[8];
  #pragma unroll
  for (int ki=0; ki<8; ++ki){
    wH[ki] = *(const bf16x8*)(whG + ki*32);
    wL[ki] = *(const bf16x8*)(wlG + ki*32);
  }
  bf16x8 wq[4];
  int nq0 = (blk&63)*16;
  if (blk < 64){
    const u16* qg = p.WqT + (size_t)(nq0+l15)*1024 + wv*128 + ko;
    #pragma unroll
    for (int ki=0; ki<4; ++ki) wq[ki] = *(const bf16x8*)(qg + ki*32);
  }
  // block-private LSTM cell state (register-resident)
  float creg = 0.f;
  if (tid < 128) creg = p.c0f[(tid>>2)*NU + u0 + (tid&3)];
  // phase-C mapping: co-locate a batch's 8 blocks on one XCD (XCD = blk%8)
  int m8 = blk>>3;
  int cb = (blk&7)*4 + (m8>>3);     // batch 0..31
  int c0 = (m8&7)*128;              // ctx col chunk
  int s0 = (m8&7)*16;               // score row chunk (C1)
  int cp = 2*(tid&63), sq8 = tid>>6;
  unsigned av[16];
  #pragma unroll
  for (int si=0; si<16; ++si)
    av[si] = *(const unsigned*)(p.aB + (size_t)(cb*128 + sq8*16 + si)*1024 + c0 + cp);
  // keys slice for C1 (rows s0+wv*2+{0,1}) — register-pinned
  u16x8 kr[2][2];
  #pragma unroll
  for (int si=0; si<2; ++si){
    const u16* kp = p.keys + (size_t)(cb*128 + s0 + wv*2 + si)*1024 + lane*16;
    kr[si][0] = *(const u16x8*)kp;
    kr[si][1] = *(const u16x8*)(kp + 8);
  }
  // v_att slice (loop-invariant)
  float vr[16];
  #pragma unroll
  for (int j=0; j<4; ++j)
    *(float4*)&vr[j*4] = *(const float4*)(p.v_att + lane*16 + j*4);

  // ===== prologue: h-waves compute h-part of z_0 (h0 @ Wr0), then swap Wr0 -> Wzh =====
  f32x4 hacc0 = f32x4{}, hacc1 = f32x4{};
  if (wv < 4){
    const unsigned* b0 = p.roll + (size_t)l15*2048 + (wv&3)*256 + ko;
    const unsigned* b1 = b0 + 16*2048;
    #pragma unroll
    for (int ki=0; ki<8; ++ki){
      uint4 x0 = *(const uint4*)(b0 + ki*32);
      uint4 y0 = *(const uint4*)(b0 + ki*32 + 4);
      uint4 x1 = *(const uint4*)(b1 + ki*32);
      uint4 y1 = *(const uint4*)(b1 + ki*32 + 4);
      bf16x8 a0h, a0l, a1h, a1l;
      unpack8(x0, y0, a0h, a0l);
      unpack8(x1, y1, a1h, a1l);
      hacc0 = MFMA(a0h, wL[ki], hacc0, 0,0,0);
      hacc0 = MFMA(a0l, wH[ki], hacc0, 0,0,0);
      hacc0 = MFMA(a0h, wH[ki], hacc0, 0,0,0);
      hacc1 = MFMA(a1h, wL[ki], hacc1, 0,0,0);
      hacc1 = MFMA(a1l, wH[ki], hacc1, 0,0,0);
      hacc1 = MFMA(a1h, wH[ki], hacc1, 0,0,0);
    }
    const u16* nh = p.WzhTH + woff;
    const u16* nl = p.WzhTL + woff;
    #pragma unroll
    for (int ki=0; ki<8; ++ki){
      wH[ki] = *(const bf16x8*)(nh + ki*32);
      wL[ki] = *(const bf16x8*)(nl + ki*32);
    }
  }

  for (int t=0; t<NT; ++t){
    unsigned g1 = 2u*t + 1u, g2 = 2u*t + 2u;
    unsigned* rollW = p.roll + (size_t)(t+1)*ROLLSTEP;   // this step's outputs
    // ---- phase A: z = xW + [precomputed h@Wzh] + ctx@Wzc -> gates -> h,c ----
    {
      float xw0=0.f, xw1=0.f, xw2=0.f, xw3=0.f;
      if (tid < 128){
        const u16* xw = p.xW + (size_t)((tid>>2)*NT + t)*4096 + u0 + (tid&3);
        xw0 = b2f(xw[0]); xw1 = b2f(xw[1024]); xw2 = b2f(xw[2048]); xw3 = b2f(xw[3072]);
      }
      f32x4 acc0, acc1;
      if (wv < 4){
        acc0 = hacc0; acc1 = hacc1;      // h-half precomputed in barrier shadow
      } else {
        acc0 = f32x4{}; acc1 = f32x4{};
        const unsigned* b0 = p.roll + (size_t)t*ROLLSTEP + 1024
                             + (size_t)l15*2048 + (wv&3)*256 + ko;
        const unsigned* b1 = b0 + 16*2048;
        #pragma unroll
        for (int ki=0; ki<8; ++ki){
          uint4 x0 = *(const uint4*)(b0 + ki*32);
          uint4 y0 = *(const uint4*)(b0 + ki*32 + 4);
          uint4 x1 = *(const uint4*)(b1 + ki*32);
          uint4 y1 = *(const uint4*)(b1 + ki*32 + 4);
          bf16x8 a0h, a0l, a1h, a1l;
          unpack8(x0, y0, a0h, a0l);
          unpack8(x1, y1, a1h, a1l);
          acc0 = MFMA(a0h, wL[ki], acc0, 0,0,0);
          acc0 = MFMA(a0l, wH[ki], acc0, 0,0,0);
          acc0 = MFMA(a0h, wH[ki], acc0, 0,0,0);
          acc1 = MFMA(a1h, wL[ki], acc1, 0,0,0);
          acc1 = MFMA(a1l, wH[ki], acc1, 0,0,0);
          acc1 = MFMA(a1h, wH[ki], acc1, 0,0,0);
        }
      }
      #pragma unroll
      for (int r=0; r<4; ++r){
        zs[wv][(lane>>4)*4 + r][l15]      = acc0[r];
        zs[wv][16 + (lane>>4)*4 + r][l15] = acc1[r];
      }
      __syncthreads();
      if (tid < 128){
        int b = tid>>2, du = tid&3;
        float zg[4];
        #pragma unroll
        for (int g=0; g<4; ++g){
          float v = 0.f;
          #pragma unroll
          for (int w=0; w<8; ++w) v += zs[w][b][g*4+du];
          zg[g] = v;
        }
        zg[0] += xw0; zg[1] += xw1; zg[2] += xw2; zg[3] += xw3;
        float i_ = sigm(zg[0]), f_ = sigm(zg[1]), g_ = tanh_(zg[2]), o_ = sigm(zg[3]);
        float cn = f_*creg + i_*g_;
        creg = cn;
        float h = o_*tanh_(cn);
        u16 hi = f2b(h), lo = f2b(h - b2f(hi));
        bstore(&rollW[b*2048 + u0 + du], ((unsigned)hi<<16)|lo);  // bypass, write-once
        size_t ho = (size_t)(b*NT + t)*2048 + u0 + du;
        p.hcH[ho] = hi; p.hcL[ho] = lo;                           // history, cached
      }
    }
    post(myflag, g1);
    // ---- phase B: q = h@W_q (blocks 0..63; others fall through to C1's q-poll) ----
    if (blk < 64){
      waitall(flags, g1, 256);
      const unsigned* b0 = rollW + (size_t)l15*2048 + wv*128 + ko;
      const unsigned* b1 = b0 + 16*2048;
      f32x4 acc0 = f32x4{}, acc1 = f32x4{};
      #pragma unroll
      for (int ki=0; ki<4; ++ki){
        uint4 x0 = *(const uint4*)(b0 + ki*32);
        uint4 y0 = *(const uint4*)(b0 + ki*32 + 4);
        uint4 x1 = *(const uint4*)(b1 + ki*32);
        uint4 y1 = *(const uint4*)(b1 + ki*32 + 4);
        bf16x8 a0h, a0l, a1h, a1l;
        unpack8(x0, y0, a0h, a0l);
        unpack8(x1, y1, a1h, a1l);
        acc0 = MFMA(a0l, wq[ki], acc0, 0,0,0);
        acc0 = MFMA(a0h, wq[ki], acc0, 0,0,0);
        acc1 = MFMA(a1l, wq[ki], acc1, 0,0,0);
        acc1 = MFMA(a1h, wq[ki], acc1, 0,0,0);
      }
      #pragma unroll
      for (int r=0; r<4; ++r){
        zs[wv][(lane>>4)*4 + r][l15]      = acc0[r];
        zs[wv][16 + (lane>>4)*4 + r][l15] = acc1[r];
      }
      __syncthreads();
      {
        int b = tid>>4, c = tid&15;
        float v = 0.f;
        #pragma unroll
        for (int w=0; w<8; ++w) v += zs[w][b][c];
        bstoref(&p.qroll[(size_t)t*32768 + b*NU + nq0 + c], v);   // bypass, write-once
      }
    }
    // ---- dataflow sync: wave 0 polls q[cb][*] for sentinel-free ----
    {
      if (tid < 64){
        const unsigned* qp = (const unsigned*)(p.qroll + (size_t)t*32768 + cb*NU) + tid*16;
        for (;;){
          uint4 a = bload4(qp), b = bload4(qp+4), c = bload4(qp+8), d = bload4(qp+12);
          bool ok = a.x!=SENT && a.y!=SENT && a.z!=SENT && a.w!=SENT
                 && b.x!=SENT && b.y!=SENT && b.z!=SENT && b.w!=SENT
                 && c.x!=SENT && c.y!=SENT && c.z!=SENT && c.w!=SENT
                 && d.x!=SENT && d.y!=SENT && d.z!=SENT && d.w!=SENT;
          if (__all(ok)) break;
          __builtin_amdgcn_s_sleep(4);
        }
      }
      __syncthreads();
    }
    // ---- phase C1: own 16 score rows (keys in registers; q cached cold, now valid) ----
    {
      const float* qp = p.qroll + (size_t)t*32768 + cb*NU + lane*16;
      float qr[16];
      #pragma unroll
      for (int j=0; j<4; ++j)
        *(float4*)&qr[j*4] = *(const float4*)(qp + j*4);
      #pragma unroll
      for (int si=0; si<2; ++si){
        float pv = 0.f;
        #pragma unroll
        for (int j=0; j<8; ++j) pv += vr[j]   * tanh_(b2f(kr[si][0][j]) + qr[j]);
        #pragma unroll
        for (int j=0; j<8; ++j) pv += vr[8+j] * tanh_(b2f(kr[si][1][j]) + qr[8+j]);
        #pragma unroll
        for (int off=32; off; off>>=1) pv += __shfl_xor(pv, off);
        if (lane==0) bstoref(&p.scroll[(size_t)t*4096 + cb*128 + s0 + wv*2 + si], pv);
      }
    }
    // ---- phase C2: dataflow-poll scores, softmax + ctx chunk (aB in registers) ----
    {
      float* alig = smem;          // [128]
      float* psum = smem + 128;    // [8][128]
      float* scl  = smem + 1280;   // [128]
      if (tid < 64){
        bool act = tid < 32;
        const unsigned* sp = (const unsigned*)(p.scroll + (size_t)t*4096 + cb*128)
                             + (act ? tid*4 : 0);
        for (;;){
          uint4 sv = bload4(sp);
          bool ok = !act || (sv.x!=SENT && sv.y!=SENT && sv.z!=SENT && sv.w!=SENT);
          if (__all(ok)){ if (act) *(uint4*)&scl[tid*4] = sv; break; }
          __builtin_amdgcn_s_sleep(2);
        }
      }
      __syncthreads();
      if (tid < 64){
        float sA = scl[tid], sB = scl[64 + tid];
        float m = fmaxf(sA, sB);
        #pragma unroll
        for (int off=32; off; off>>=1) m = fmaxf(m, __shfl_xor(m, off));
        float e0 = __expf(sA-m), e1 = __expf(sB-m);
        float sum = e0+e1;
        #pragma unroll
        for (int off=32; off; off>>=1) sum += __shfl_xor(sum, off);
        float inv = frcp(sum);
        alig[tid] = e0*inv; alig[tid+64] = e1*inv;
      }
      __syncthreads();
      {
        float ax = 0.f, ay = 0.f;
        #pragma unroll
        for (int si=0; si<16; ++si){
          unsigned kv = av[si];
          float al = alig[sq8*16 + si];
          ax += al*b2f((u16)(kv & 0xffffu));
          ay += al*b2f((u16)(kv >> 16));
        }
        psum[sq8*128 + cp]   = ax;
        psum[sq8*128 + cp+1] = ay;
      }
      __syncthreads();
      if (tid < 128){
        float v = 0.f;
        #pragma unroll
        for (int s8=0; s8<8; ++s8) v += psum[s8*128 + tid];
        int col = c0 + tid;
        u16 hi = f2b(v), lo = f2b(v - b2f(hi));
        bstore(&rollW[cb*2048 + 1024 + col], ((unsigned)hi<<16)|lo);  // bypass, write-once
        size_t ho = (size_t)(cb*NT + t)*2048 + 1024 + col;
        p.hcH[ho] = hi; p.hcL[ho] = lo;                               // history, cached
      }
    }
    post(myflag, g2);
    // ---- barrier shadow: h-waves precompute NEXT step's h-part of z ----
    // legal: this step's q-poll passed => all of roll[t+1].h is committed, and
    // h lines (cols 0..1023) never share a 128B line with ctx (cols 1024..2047).
    if (wv < 4 && t < NT-1){
      const unsigned* b0 = rollW + (size_t)l15*2048 + (wv&3)*256 + ko;
      const unsigned* b1 = b0 + 16*2048;
      hacc0 = f32x4{}; hacc1 = f32x4{};
      #pragma unroll
      for (int ki=0; ki<8; ++ki){
        uint4 x0 = *(const uint4*)(b0 + ki*32);
        uint4 y0 = *(const uint4*)(b0 + ki*32 + 4);
        uint4 x1 = *(const uint4*)(b1 + ki*32);
        uint4 y1 = *(const uint4*)(b1 + ki*32 + 4);
        bf16x8 a0h, a0l, a1h, a1l;
        unpack8(x0, y0, a0h, a0l);
        unpack8(x1, y1, a1h, a1l);
        hacc0 = MFMA(a0h, wL[ki], hacc0, 0,0,0);
        hacc0 = MFMA(a0l, wH[ki], hacc0, 0,0,0);
        hacc0 = MFMA(a0h, wH[ki], hacc0, 0,0,0);
        hacc1 = MFMA(a1h, wL[ki], hacc1, 0,0,0);
        hacc1 = MFMA(a1l, wH[ki], hacc1, 0,0,0);
        hacc1 = MFMA(a1h, wH[ki], hacc1, 0,0,0);
      }
    }
    waitall(flags, g2, 256);
  }
}

// ---------------- logits: 128x128-tile, BK=32, global_load_lds staging (m97-style) ----
__global__ __launch_bounds__(256) void k_logits(
    const u16* __restrict__ A,   // [4096][1024]
    const u16* __restrict__ Bt,  // [32000][1024]
    const float* __restrict__ bias,
    float* __restrict__ C)
{
  __shared__ __align__(16) u16 As[128*32];
  __shared__ __align__(16) u16 Bs[128*32];
  int tid = threadIdx.x, lane = tid&63, wv = tid>>6;
  int m0 = blockIdx.y*128, n0 = blockIdx.x*128;
  int wr = (wv>>1)*64, wc = (wv&1)*64;
  int l15 = lane&15, ko = (lane>>4)*8;
  int srow = lane>>2, scol = (lane&3)*8;   // within 16-row chunk: lane covers row srow, cols scol..scol+8
  f32x4 acc[4][4] = {};
  for (int kk=0; kk<1024; kk+=32){
    #pragma unroll
    for (int i=0; i<2; ++i){
      int c = wv*2 + i;                    // chunk 0..7 (16 rows each)
      const u16* ga = A  + (size_t)(m0 + c*16 + srow)*1024 + kk + scol;
      const u16* gb = Bt + (size_t)(n0 + c*16 + srow)*1024 + kk + scol;
      __builtin_amdgcn_global_load_lds((GU*)ga, (LU*)(As + c*512), 16, 0, 0);
      __builtin_amdgcn_global_load_lds((GU*)gb, (LU*)(Bs + c*512), 16, 0, 0);
    }
    asm volatile("s_waitcnt vmcnt(0)" ::: "memory");
    __syncthreads();
    bf16x8 af[4], bf[4];
    #pragma unroll
    for (int i=0;i<4;++i){
      af[i] = *(const bf16x8*)(As + (wr+i*16+l15)*32 + ko);
      bf[i] = *(const bf16x8*)(Bs + (wc+i*16+l15)*32 + ko);
    }
    #pragma unroll
    for (int mi=0;mi<4;++mi)
      #pragma unroll
      for (int ni=0;ni<4;++ni)
        acc[mi][ni] = MFMA(af[mi], bf[ni], acc[mi][ni], 0,0,0);
    __syncthreads();
  }
  #pragma unroll
  for (int mi=0; mi<4; ++mi){
    int row = m0 + wr + mi*16 + (lane>>4)*4;
    #pragma unroll
    for (int ni=0; ni<4; ++ni){
      int col = n0 + wc + ni*16 + l15;
      float bval = bias[col];
      #pragma unroll
      for (int r=0; r<4; ++r){
        if (row + r < NB*NT)
          C[(size_t)(row+r)*NV + col] = acc[mi][ni][r] + bval;
      }
    }
  }
}

// ---------------- host ----------------
extern "C" void kernel_launch(void* const* d_in, const int* in_sizes, int n_in,
                              void* d_out, int out_size, void* d_ws, size_t ws_size,
                              hipStream_t stream)
{
  (void)in_sizes; (void)n_in; (void)out_size; (void)ws_size;
  const int*   toks  = (const int*)  d_in[0];
  const float* a_in  = (const float*)d_in[1];
  const float* a_tx  = (const float*)d_in[2];
  const float* c_tx  = (const float*)d_in[3];
  const float* emb   = (const float*)d_in[4];
  const float* W_k   = (const float*)d_in[5];
  const float* W_r   = (const float*)d_in[6];
  const float* bvec  = (const float*)d_in[7];
  const float* W_m   = (const float*)d_in[8];
  const float* W_q   = (const float*)d_in[9];
  const float* v_att = (const float*)d_in[10];
  const float* W_a   = (const float*)d_in[11];
  const float* W_o   = (const float*)d_in[12];
  const float* b_o   = (const float*)d_in[13];
  float* out = (float*)d_out;

  char* p = (char*)d_ws;
  auto alloc = [&](size_t bytes)->char*{ char* r = p; p += (bytes + 255) & ~(size_t)255; return r; };

  u16* WzhTH = (u16*)alloc((size_t)4096*1024*2);
  u16* WzhTL = (u16*)alloc((size_t)4096*1024*2);
  u16* WzcTH = (u16*)alloc((size_t)4096*1024*2);
  u16* WzcTL = (u16*)alloc((size_t)4096*1024*2);
  u16* Wr0TH = (u16*)alloc((size_t)4096*1024*2);   // reused as outsH after persist
  u16* Wr0TL = (u16*)alloc((size_t)4096*1024*2);
  u16* WqT   = (u16*)alloc((size_t)1024*1024*2);
  u16* WaTH  = (u16*)alloc((size_t)1024*2048*2);
  u16* WaTL  = (u16*)alloc((size_t)1024*2048*2);
  u16* WmT   = (u16*)alloc((size_t)1024*1024*2);
  u16* WoT   = (u16*)alloc((size_t)NV*1024*2);
  u16* WkxT  = (u16*)alloc((size_t)4096*256*2);
  u16* xB    = (u16*)alloc((size_t)4096*256*2);
  u16* xWb   = (u16*)alloc((size_t)4096*4096*2);
  u16* aB    = (u16*)alloc((size_t)4096*1024*2);
  u16* keysB = (u16*)alloc((size_t)4096*1024*2);
  // union region: prep { WkaT h/l, WaRow h/l, tmpF } -> persist { hcH, hcL }
  char* uni  = alloc((size_t)44*1024*1024);
  u16* WkaTH  = (u16*)uni;
  u16* WkaTL  = WkaTH + (size_t)4096*1024;
  u16* WaRowH = WkaTL + (size_t)4096*1024;
  u16* WaRowL = WaRowH + (size_t)2048*1024;
  float* tmpF = (float*)(WaRowL + (size_t)2048*1024);
  u16* hcH = (u16*)uni;
  u16* hcL = hcH + (size_t)4096*2048;

  unsigned* roll   = (unsigned*)alloc((size_t)(NT+1)*ROLLSTEP*4);   // 33.6 MB
  float*    qroll  = (float*)alloc((size_t)NT*NB*NU*4);             // 16.6 MB
  float*    scroll = (float*)alloc((size_t)NT*NB*128*4);            // 2.1 MB
  unsigned* flags  = (unsigned*)alloc(4096);
  u16* outsH = Wr0TH;   // overlap (Wr0T dead after persist prologue)

  // ---- init ----
  (void)hipMemsetAsync(flags, 0, 4096, stream);
  (void)hipMemsetAsync(roll, 0, (size_t)ROLLSTEP*4, stream);   // slot 0 (ctx0 = 0)
  (void)hipMemsetAsync(qroll, 0xFF, (size_t)NT*NB*NU*4, stream);     // sentinel
  (void)hipMemsetAsync(scroll, 0xFF, (size_t)NT*NB*128*4, stream);   // sentinel
  k_pack0<<<128,256,0,stream>>>(a_tx, roll);
  k_split<<<2048,256,0,stream>>>(W_a, WaRowH, WaRowL, 2048*1024);
  k_gather<<<(NB*NT*NE)/256,256,0,stream>>>(toks, emb, xB);
  k_conv<<<2048,256,0,stream>>>(a_in, aB, NB*128*NU);

  // ---- weight transposes ----
  k_transpose<<<dim3(128,32),256,0,stream>>>(W_k + (size_t)256*4096, 4096, WkaTH, WkaTL, 1024, 0);
  k_transpose<<<dim3(128,32),256,0,stream>>>(W_r, 4096, Wr0TH, Wr0TL, 1024, 0);
  k_transpose<<<dim3(32,32),256,0,stream>>>(W_q, 1024, WqT, nullptr, 1024, 0);
  k_transpose<<<dim3(32,64),256,0,stream>>>(W_a, 1024, WaTH, WaTL, 2048, 0);
  k_transpose<<<dim3(32,32),256,0,stream>>>(W_m, 1024, WmT, nullptr, 1024, 0);
  k_transpose<<<dim3(1000,32),256,0,stream>>>(W_o, NV, WoT, nullptr, 1024, 0);
  k_transpose<<<dim3(128,8),256,0,stream>>>(W_k, 4096, WkxT, nullptr, 256, 0);

  // ---- precompute GEMMs ----
  // keys = a @ W_m
  k_gemm64<1,0><<<dim3(16,64),256,0,stream>>>(aB, 1024, WmT, 1024, nullptr, keysB, 1024, nullptr, 4096, 1024);
  // xW = x @ W_k[0:256] + b
  k_gemm64<1,1><<<dim3(64,64),256,0,stream>>>(xB, 256, WkxT, 256, nullptr, xWb, 4096, bvec, NB*NT, 256);
  // Wzh = W_r + W_a[0:1024] @ Wk_attn  (3-term split, f32, then transpose+split)
  k_gemm128s<0><<<dim3(32,8),256,0,stream>>>(WaRowH, WaRowL, 1024, WkaTH, WkaTL, 1024,
                                             tmpF, nullptr, 4096, 1024, 1024);
  k_fuseT<<<dim3(128,32),256,0,stream>>>(tmpF, W_r, WzhTH, WzhTL);
  // Wzc = W_a[1024:2048] @ Wk_attn
  k_gemm128s<0><<<dim3(32,8),256,0,stream>>>(WaRowH + (size_t)1024*1024, WaRowL + (size_t)1024*1024, 1024,
                                             WkaTH, WkaTL, 1024, tmpF, nullptr, 4096, 1024, 1024);
  k_fuseT<<<dim3(128,32),256,0,stream>>>(tmpF, nullptr, WzcTH, WzcTL);

  // ---- persistent recurrence ----
  PP pp;
  pp.WzhTH=WzhTH; pp.WzhTL=WzhTL; pp.WzcTH=WzcTH; pp.WzcTL=WzcTL;
  pp.Wr0TH=Wr0TH; pp.Wr0TL=Wr0TL; pp.WqT=WqT; pp.xW=xWb;
  pp.keys=keysB; pp.aB=aB; pp.v_att=v_att; pp.c0f=c_tx;
  pp.roll=roll; pp.qroll=qroll; pp.scroll=scroll;
  pp.hcH=hcH; pp.hcL=hcL; pp.flags=flags;
  k_persist<<<NBLK,512,0,stream>>>(pp);

  // ---- outs = [h|ctx] @ W_a  (3-term split, bf16 out, 128-tile) ----
  k_gemm128s<1><<<dim3(8,32),256,0,stream>>>(hcH, hcL, 2048, WaTH, WaTL, 2048,
                                             nullptr, outsH, 1024, NB*NT, 2048);

  // ---- logits = outs @ W_o + b_o ----
  k_logits<<<dim3(NV/128, 32),256,0,stream>>>(outsH, WoT, b_o, out);
}